// Round 1
// baseline (1525.838 us; speedup 1.0000x reference)
//
#include <hip/hip_runtime.h>
#include <hip/hip_bf16.h>

// GAT fused layer for MI355X.
// Inputs (f32 unless noted): h[N,128], W[8,128,8], a1[8,8], a2[8,8], src[E] i32, dst[E] i32
// Output: f32 [N, 64]
//
// Pipeline:
//   K1 gemm_s_kernel : Wh = h @ W'  (+ fused s_src/s_dst epilogue)
//   memset           : denom = 0, out = 0
//   K2 denom_kernel  : denom[d,h] += exp(lrelu(s_src[s,h]+s_dst[d,h]))   (max-pass elided; see notes)
//   K3 scatter_kernel: out[d,:] += (p/denom[d,h]) * Wh[s,h,:]

#define NODES 50000
#define EDGES 800000
#define FIN 128
#define NH 8
#define NO 8
#define NC 64  // NH*NO

__global__ __launch_bounds__(256) void gemm_s_kernel(
    const float* __restrict__ h, const float* __restrict__ W,
    const float* __restrict__ a1, const float* __restrict__ a2,
    float* __restrict__ Wh, float* __restrict__ s_src, float* __restrict__ s_dst,
    int N)
{
    __shared__ float Ws[FIN][NC];    // 32 KB, B-matrix in [f][h*8+o] layout
    __shared__ float hs[32][FIN];    // 16 KB
    const int tid = threadIdx.x;
    const int row0 = blockIdx.x * 32;

    // stage W permuted: Ws[f][c] = W[h][f][o], c = h*8+o
    for (int i = tid; i < FIN * NC; i += 256) {
        int f = i >> 6, c = i & 63;
        Ws[f][c] = W[(c >> 3) * (FIN * NO) + f * NO + (c & 7)];
    }
    // stage 32 rows of h (coalesced)
    for (int i = tid; i < 32 * FIN; i += 256) {
        int r = i >> 7, f = i & 127;
        int n = row0 + r;
        hs[r][f] = (n < N) ? h[(long)n * FIN + f] : 0.f;
    }
    __syncthreads();

    const int c  = tid & 63;         // output column = lane id
    const int r0 = (tid >> 6) * 8;   // 8 rows per thread
    const float a1c = a1[c];
    const float a2c = a2[c];

    float acc[8];
#pragma unroll
    for (int rr = 0; rr < 8; ++rr) acc[rr] = 0.f;

    for (int f = 0; f < FIN; ++f) {
        float w = Ws[f][c];          // 2-way bank alias: free
#pragma unroll
        for (int rr = 0; rr < 8; ++rr)
            acc[rr] += hs[r0 + rr][f] * w;   // broadcast read
    }

#pragma unroll
    for (int rr = 0; rr < 8; ++rr) {
        int n = row0 + r0 + rr;
        bool ok = (n < N);
        if (ok) Wh[(long)n * NC + c] = acc[rr];
        // fused s_src/s_dst: reduce over o (8 consecutive lanes per head)
        float ps = acc[rr] * a1c;
        float pd = acc[rr] * a2c;
        ps += __shfl_xor(ps, 1); pd += __shfl_xor(pd, 1);
        ps += __shfl_xor(ps, 2); pd += __shfl_xor(pd, 2);
        ps += __shfl_xor(ps, 4); pd += __shfl_xor(pd, 4);
        if (ok && (c & 7) == 0) {
            s_src[n * NH + (c >> 3)] = ps;
            s_dst[n * NH + (c >> 3)] = pd;
        }
    }
}

__global__ __launch_bounds__(256) void denom_kernel(
    const int* __restrict__ src, const int* __restrict__ dst,
    const float* __restrict__ s_src, const float* __restrict__ s_dst,
    float* __restrict__ denom, int E)
{
    long idx = (long)blockIdx.x * blockDim.x + threadIdx.x;
    if (idx >= (long)E * NH) return;
    int e  = (int)(idx >> 3);
    int hh = (int)(idx & 7);
    int s = src[e], d = dst[e];
    float v = s_src[s * NH + hh] + s_dst[d * NH + hh];
    v = (v > 0.f) ? v : 0.2f * v;          // leaky_relu
    float p = __expf(v);                   // shift-invariant softmax: no max pass needed
    atomicAdd(&denom[d * NH + hh], p);
}

__global__ __launch_bounds__(256) void scatter_kernel(
    const int* __restrict__ src, const int* __restrict__ dst,
    const float* __restrict__ s_src, const float* __restrict__ s_dst,
    const float* __restrict__ denom, const float* __restrict__ Wh,
    float* __restrict__ out, int E)
{
    long idx = (long)blockIdx.x * blockDim.x + threadIdx.x;
    if (idx >= (long)E * NH) return;
    int e  = (int)(idx >> 3);
    int hh = (int)(idx & 7);
    int s = src[e], d = dst[e];
    float v = s_src[s * NH + hh] + s_dst[d * NH + hh];
    v = (v > 0.f) ? v : 0.2f * v;
    float p = __expf(v);
    float den = denom[d * NH + hh];
    float attn = p / fmaxf(den, 1e-16f);

    const float4* whp = (const float4*)(Wh + (long)s * NC + hh * NO);
    float4 w0 = whp[0];
    float4 w1 = whp[1];
    float* op = out + (long)d * NC + hh * NO;
    atomicAdd(op + 0, attn * w0.x);
    atomicAdd(op + 1, attn * w0.y);
    atomicAdd(op + 2, attn * w0.z);
    atomicAdd(op + 3, attn * w0.w);
    atomicAdd(op + 4, attn * w1.x);
    atomicAdd(op + 5, attn * w1.y);
    atomicAdd(op + 6, attn * w1.z);
    atomicAdd(op + 7, attn * w1.w);
}

extern "C" void kernel_launch(void* const* d_in, const int* in_sizes, int n_in,
                              void* d_out, int out_size, void* d_ws, size_t ws_size,
                              hipStream_t stream)
{
    const float* h  = (const float*)d_in[0];
    const float* W  = (const float*)d_in[1];
    const float* a1 = (const float*)d_in[2];
    const float* a2 = (const float*)d_in[3];
    const int*  src = (const int*)d_in[4];
    const int*  dst = (const int*)d_in[5];
    float* out = (float*)d_out;

    const int N = in_sizes[0] / FIN;   // 50000
    const int E = in_sizes[4];         // 800000

    // workspace layout
    float* ws    = (float*)d_ws;
    float* Wh    = ws;                        // N*64
    float* s_src = Wh + (long)N * NC;         // N*8
    float* s_dst = s_src + (long)N * NH;      // N*8
    float* denom = s_dst + (long)N * NH;      // N*8

    hipMemsetAsync(out, 0, (size_t)out_size * sizeof(float), stream);
    hipMemsetAsync(denom, 0, (size_t)N * NH * sizeof(float), stream);

    int gemm_blocks = (N + 31) / 32;
    gemm_s_kernel<<<gemm_blocks, 256, 0, stream>>>(h, W, a1, a2, Wh, s_src, s_dst, N);

    long eh = (long)E * NH;
    int eh_blocks = (int)((eh + 255) / 256);
    denom_kernel<<<eh_blocks, 256, 0, stream>>>(src, dst, s_src, s_dst, denom, E);
    scatter_kernel<<<eh_blocks, 256, 0, stream>>>(src, dst, s_src, s_dst, denom, Wh, out, E);
}

// Round 2
// 223.627 us; speedup vs baseline: 6.8231x; 6.8231x over previous
//
#include <hip/hip_runtime.h>
#include <hip/hip_bf16.h>

// GAT fused layer for MI355X — round 2: atomic-free scatter via dst-CSR.
//
// Pipeline:
//   K1 gemm_s_kernel : Wh = h @ W'  (+ fused s_src/s_dst epilogue)
//   memset cnt=0 ; K2 hist ; K3-K5 scan (block/partials/add) ; memset cnt=0 ; K6 fill
//   K7 gather_kernel : per dst-node wave: out[d,c] = sum_e p*Wh[s,c] / sum_e p

#define FIN 128
#define NH 8
#define NO 8
#define NC 64
#define SCAN_BLK 256

__global__ __launch_bounds__(256) void gemm_s_kernel(
    const float* __restrict__ h, const float* __restrict__ W,
    const float* __restrict__ a1, const float* __restrict__ a2,
    float* __restrict__ Wh, float* __restrict__ s_src, float* __restrict__ s_dst,
    int N)
{
    __shared__ float Ws[FIN][NC];    // 32 KB, B-matrix in [f][h*8+o] layout
    __shared__ float hs[32][FIN];    // 16 KB
    const int tid = threadIdx.x;
    const int row0 = blockIdx.x * 32;

    for (int i = tid; i < FIN * NC; i += 256) {
        int f = i >> 6, c = i & 63;
        Ws[f][c] = W[(c >> 3) * (FIN * NO) + f * NO + (c & 7)];
    }
    for (int i = tid; i < 32 * FIN; i += 256) {
        int r = i >> 7, f = i & 127;
        int n = row0 + r;
        hs[r][f] = (n < N) ? h[(long)n * FIN + f] : 0.f;
    }
    __syncthreads();

    const int c  = tid & 63;
    const int r0 = (tid >> 6) * 8;
    const float a1c = a1[c];
    const float a2c = a2[c];

    float acc[8];
#pragma unroll
    for (int rr = 0; rr < 8; ++rr) acc[rr] = 0.f;

    for (int f = 0; f < FIN; ++f) {
        float w = Ws[f][c];
#pragma unroll
        for (int rr = 0; rr < 8; ++rr)
            acc[rr] += hs[r0 + rr][f] * w;
    }

#pragma unroll
    for (int rr = 0; rr < 8; ++rr) {
        int n = row0 + r0 + rr;
        bool ok = (n < N);
        if (ok) Wh[(long)n * NC + c] = acc[rr];
        float ps = acc[rr] * a1c;
        float pd = acc[rr] * a2c;
        ps += __shfl_xor(ps, 1); pd += __shfl_xor(pd, 1);
        ps += __shfl_xor(ps, 2); pd += __shfl_xor(pd, 2);
        ps += __shfl_xor(ps, 4); pd += __shfl_xor(pd, 4);
        if (ok && (c & 7) == 0) {
            s_src[n * NH + (c >> 3)] = ps;
            s_dst[n * NH + (c >> 3)] = pd;
        }
    }
}

__global__ __launch_bounds__(256) void hist_kernel(
    const int* __restrict__ dst, int* __restrict__ cnt, int E)
{
    int e = blockIdx.x * 256 + threadIdx.x;
    if (e < E) atomicAdd(&cnt[dst[e]], 1);
}

__global__ __launch_bounds__(256) void scan1_kernel(
    const int* __restrict__ cnt, int* __restrict__ row_off,
    int* __restrict__ partials, int N)
{
    __shared__ int sm[SCAN_BLK];
    int i = blockIdx.x * SCAN_BLK + threadIdx.x;
    int v = (i < N) ? cnt[i] : 0;
    sm[threadIdx.x] = v;
    __syncthreads();
    for (int off = 1; off < SCAN_BLK; off <<= 1) {
        int t = (threadIdx.x >= off) ? sm[threadIdx.x - off] : 0;
        __syncthreads();
        sm[threadIdx.x] += t;
        __syncthreads();
    }
    if (i < N) row_off[i] = sm[threadIdx.x] - v;   // exclusive within block
    if (threadIdx.x == SCAN_BLK - 1) partials[blockIdx.x] = sm[SCAN_BLK - 1];
}

__global__ __launch_bounds__(256) void scan2_kernel(int* __restrict__ partials, int nblk)
{
    __shared__ int sm[SCAN_BLK];
    int v = (threadIdx.x < nblk) ? partials[threadIdx.x] : 0;
    sm[threadIdx.x] = v;
    __syncthreads();
    for (int off = 1; off < SCAN_BLK; off <<= 1) {
        int t = (threadIdx.x >= off) ? sm[threadIdx.x - off] : 0;
        __syncthreads();
        sm[threadIdx.x] += t;
        __syncthreads();
    }
    if (threadIdx.x < nblk) partials[threadIdx.x] = sm[threadIdx.x] - v;  // exclusive
}

__global__ __launch_bounds__(256) void scan3_kernel(
    int* __restrict__ row_off, const int* __restrict__ partials, int N, int E)
{
    int i = blockIdx.x * SCAN_BLK + threadIdx.x;
    if (i < N) row_off[i] += partials[blockIdx.x];
    if (blockIdx.x == 0 && threadIdx.x == 0) row_off[N] = E;
}

__global__ __launch_bounds__(256) void fill_kernel(
    const int* __restrict__ src, const int* __restrict__ dst,
    int* __restrict__ cnt, const int* __restrict__ row_off,
    int* __restrict__ srcs, int E)
{
    int e = blockIdx.x * 256 + threadIdx.x;
    if (e >= E) return;
    int d = dst[e];
    int pos = atomicAdd(&cnt[d], 1);
    srcs[row_off[d] + pos] = src[e];   // store src id directly (saves an indirection)
}

__global__ __launch_bounds__(256) void gather_kernel(
    const int* __restrict__ srcs, const int* __restrict__ row_off,
    const float* __restrict__ s_src, const float* __restrict__ s_dst,
    const float* __restrict__ Wh, float* __restrict__ out, int N)
{
    int wid = blockIdx.x * 4 + (threadIdx.x >> 6);   // one wave per dst node
    if (wid >= N) return;
    const int lane = threadIdx.x & 63;
    const int hh = lane >> 3;
    int beg = row_off[wid];
    int end = row_off[wid + 1];
    float sd = s_dst[wid * NH + hh];
    float acc = 0.f, den = 0.f;
    for (int i = beg; i < end; ++i) {
        int s = srcs[i];
        float ss = s_src[s * NH + hh];
        float v = ss + sd;
        v = (v > 0.f) ? v : 0.2f * v;          // leaky_relu
        float p = __expf(v);                   // shift-invariant softmax, no max pass
        den += p;
        acc = fmaf(p, Wh[(long)s * NC + lane], acc);
    }
    out[(long)wid * NC + lane] = acc / fmaxf(den, 1e-16f);
}

extern "C" void kernel_launch(void* const* d_in, const int* in_sizes, int n_in,
                              void* d_out, int out_size, void* d_ws, size_t ws_size,
                              hipStream_t stream)
{
    const float* h  = (const float*)d_in[0];
    const float* W  = (const float*)d_in[1];
    const float* a1 = (const float*)d_in[2];
    const float* a2 = (const float*)d_in[3];
    const int*  src = (const int*)d_in[4];
    const int*  dst = (const int*)d_in[5];
    float* out = (float*)d_out;

    const int N = in_sizes[0] / FIN;   // 50000
    const int E = in_sizes[4];         // 800000

    // workspace layout (all 4-byte aligned)
    char* wsb = (char*)d_ws;
    float* Wh    = (float*)wsb;                         wsb += (size_t)N * NC * 4;
    float* s_src = (float*)wsb;                         wsb += (size_t)N * NH * 4;
    float* s_dst = (float*)wsb;                         wsb += (size_t)N * NH * 4;
    int* row_off = (int*)wsb;                           wsb += (size_t)(N + 1) * 4;
    int* cnt     = (int*)wsb;                           wsb += (size_t)N * 4;
    int* partials= (int*)wsb;                           wsb += (size_t)SCAN_BLK * 4;
    int* srcs    = (int*)wsb;                           wsb += (size_t)E * 4;

    const int nblk = (N + SCAN_BLK - 1) / SCAN_BLK;    // 196 <= 256

    int gemm_blocks = (N + 31) / 32;
    gemm_s_kernel<<<gemm_blocks, 256, 0, stream>>>(h, W, a1, a2, Wh, s_src, s_dst, N);

    hipMemsetAsync(cnt, 0, (size_t)N * 4, stream);
    int e_blocks = (E + 255) / 256;
    hist_kernel<<<e_blocks, 256, 0, stream>>>(dst, cnt, E);
    scan1_kernel<<<nblk, SCAN_BLK, 0, stream>>>(cnt, row_off, partials, N);
    scan2_kernel<<<1, SCAN_BLK, 0, stream>>>(partials, nblk);
    scan3_kernel<<<nblk, SCAN_BLK, 0, stream>>>(row_off, partials, N, E);
    hipMemsetAsync(cnt, 0, (size_t)N * 4, stream);
    fill_kernel<<<e_blocks, 256, 0, stream>>>(src, dst, cnt, row_off, srcs, E);

    int g_blocks = (N + 3) / 4;
    gather_kernel<<<g_blocks, 256, 0, stream>>>(srcs, row_off, s_src, s_dst, Wh, out, N);
}

// Round 3
// 159.203 us; speedup vs baseline: 9.5842x; 1.4047x over previous
//
#include <hip/hip_runtime.h>
#include <hip/hip_bf16.h>
#include <hip/hip_fp16.h>

// GAT fused layer for MI355X — round 3.
//   K1 gemm_s_hist : Wh(fp16) = h @ W'  + s_src/s_dst epilogue + fused dst histogram
//   K2-K4 scan     : exclusive scan of cnt -> row_off
//   K5 fill        : CSR fill, atomicAdd on row_off itself (old value = slot)
//   K6 gather      : per dst-node wave, unroll-4 edge loop, fp16 Wh gathers

#define FIN 128
#define NH 8
#define NO 8
#define NC 64
#define SCAN_BLK 256

__global__ __launch_bounds__(256) void gemm_s_hist_kernel(
    const float* __restrict__ h, const float* __restrict__ W,
    const float* __restrict__ a1, const float* __restrict__ a2,
    const int* __restrict__ dst, int* __restrict__ cnt,
    __half* __restrict__ Wh, float* __restrict__ s_src, float* __restrict__ s_dst,
    int N, int E)
{
    __shared__ float Ws[FIN][NC];    // 32 KB
    __shared__ float hs[32][FIN];    // 16 KB
    const int tid = threadIdx.x;
    const int row0 = blockIdx.x * 32;

    // fused dst-histogram (fire-and-forget atomics, hidden under gemm)
    for (long e = (long)blockIdx.x * 256 + tid; e < E; e += (long)gridDim.x * 256)
        atomicAdd(&cnt[dst[e]], 1);

    // stage W permuted: Ws[f][c] = W[h][f][o], c = h*8+o
    for (int i = tid; i < FIN * NC; i += 256) {
        int f = i >> 6, c = i & 63;
        Ws[f][c] = W[(c >> 3) * (FIN * NO) + f * NO + (c & 7)];
    }
    // stage 32 rows of h via float4 (coalesced)
    const float4* h4 = (const float4*)(h + (long)row0 * FIN);
    for (int i = tid; i < 32 * (FIN / 4); i += 256) {
        int r = i >> 5;                       // FIN/4 == 32 float4 per row
        int n = row0 + r;
        float4 v = (n < N) ? h4[i] : make_float4(0.f, 0.f, 0.f, 0.f);
        *(float4*)&hs[r][(i & 31) * 4] = v;
    }
    __syncthreads();

    const int c  = tid & 63;         // output column
    const int r0 = (tid >> 6) * 8;   // 8 rows per thread
    const float a1c = a1[c];
    const float a2c = a2[c];

    float acc[8];
#pragma unroll
    for (int rr = 0; rr < 8; ++rr) acc[rr] = 0.f;

    for (int f = 0; f < FIN; f += 4) {
        float w0 = Ws[f + 0][c], w1 = Ws[f + 1][c];
        float w2 = Ws[f + 2][c], w3 = Ws[f + 3][c];
#pragma unroll
        for (int rr = 0; rr < 8; ++rr) {
            float4 hv = *(const float4*)&hs[r0 + rr][f];   // broadcast b128: free
            acc[rr] = fmaf(hv.x, w0, acc[rr]);
            acc[rr] = fmaf(hv.y, w1, acc[rr]);
            acc[rr] = fmaf(hv.z, w2, acc[rr]);
            acc[rr] = fmaf(hv.w, w3, acc[rr]);
        }
    }

#pragma unroll
    for (int rr = 0; rr < 8; ++rr) {
        int n = row0 + r0 + rr;
        bool ok = (n < N);
        if (ok) Wh[(long)n * NC + c] = __float2half_rn(acc[rr]);
        float ps = acc[rr] * a1c;
        float pd = acc[rr] * a2c;
        ps += __shfl_xor(ps, 1); pd += __shfl_xor(pd, 1);
        ps += __shfl_xor(ps, 2); pd += __shfl_xor(pd, 2);
        ps += __shfl_xor(ps, 4); pd += __shfl_xor(pd, 4);
        if (ok && (c & 7) == 0) {
            s_src[n * NH + (c >> 3)] = ps;
            s_dst[n * NH + (c >> 3)] = pd;
        }
    }
}

__global__ __launch_bounds__(256) void scan1_kernel(
    const int* __restrict__ cnt, int* __restrict__ row_off,
    int* __restrict__ partials, int N)
{
    __shared__ int sm[SCAN_BLK];
    int i = blockIdx.x * SCAN_BLK + threadIdx.x;
    int v = (i < N) ? cnt[i] : 0;
    sm[threadIdx.x] = v;
    __syncthreads();
    for (int off = 1; off < SCAN_BLK; off <<= 1) {
        int t = (threadIdx.x >= off) ? sm[threadIdx.x - off] : 0;
        __syncthreads();
        sm[threadIdx.x] += t;
        __syncthreads();
    }
    if (i < N) row_off[i] = sm[threadIdx.x] - v;   // exclusive within block
    if (threadIdx.x == SCAN_BLK - 1) partials[blockIdx.x] = sm[SCAN_BLK - 1];
}

__global__ __launch_bounds__(256) void scan2_kernel(int* __restrict__ partials, int nblk)
{
    __shared__ int sm[SCAN_BLK];
    int v = (threadIdx.x < nblk) ? partials[threadIdx.x] : 0;
    sm[threadIdx.x] = v;
    __syncthreads();
    for (int off = 1; off < SCAN_BLK; off <<= 1) {
        int t = (threadIdx.x >= off) ? sm[threadIdx.x - off] : 0;
        __syncthreads();
        sm[threadIdx.x] += t;
        __syncthreads();
    }
    if (threadIdx.x < nblk) partials[threadIdx.x] = sm[threadIdx.x] - v;  // exclusive
}

__global__ __launch_bounds__(256) void scan3_kernel(
    int* __restrict__ row_off, const int* __restrict__ partials, int N)
{
    int i = blockIdx.x * SCAN_BLK + threadIdx.x;
    if (i < N) row_off[i] += partials[blockIdx.x];
}

// CSR fill: atomicAdd on row_off itself; returned old value is the slot.
// Afterwards row_off[d] == exclusive_scan[d+1], so gather uses beg=row_off[d-1].
__global__ __launch_bounds__(256) void fill_kernel(
    const int* __restrict__ src, const int* __restrict__ dst,
    int* __restrict__ row_off, int* __restrict__ srcs, int E)
{
    int e = blockIdx.x * 256 + threadIdx.x;
    if (e >= E) return;
    int pos = atomicAdd(&row_off[dst[e]], 1);
    srcs[pos] = src[e];
}

__global__ __launch_bounds__(256) void gather_kernel(
    const int* __restrict__ srcs, const int* __restrict__ row_off,
    const float* __restrict__ s_src, const float* __restrict__ s_dst,
    const __half* __restrict__ Wh, float* __restrict__ out, int N)
{
    int wid = blockIdx.x * 4 + (threadIdx.x >> 6);   // one wave per dst node
    if (wid >= N) return;
    const int lane = threadIdx.x & 63;
    const int hh = lane >> 3;
    int beg = (wid == 0) ? 0 : row_off[wid - 1];
    int end = row_off[wid];
    float sd = s_dst[wid * NH + hh];
    float acc = 0.f, den = 0.f;
    int i = beg;
    for (; i + 4 <= end; i += 4) {
        int s0 = srcs[i + 0], s1 = srcs[i + 1], s2 = srcs[i + 2], s3 = srcs[i + 3];
        float ss0 = s_src[s0 * NH + hh], ss1 = s_src[s1 * NH + hh];
        float ss2 = s_src[s2 * NH + hh], ss3 = s_src[s3 * NH + hh];
        float w0 = __half2float(Wh[(long)s0 * NC + lane]);
        float w1 = __half2float(Wh[(long)s1 * NC + lane]);
        float w2 = __half2float(Wh[(long)s2 * NC + lane]);
        float w3 = __half2float(Wh[(long)s3 * NC + lane]);
        float v0 = ss0 + sd; v0 = (v0 > 0.f) ? v0 : 0.2f * v0; float p0 = __expf(v0);
        float v1 = ss1 + sd; v1 = (v1 > 0.f) ? v1 : 0.2f * v1; float p1 = __expf(v1);
        float v2 = ss2 + sd; v2 = (v2 > 0.f) ? v2 : 0.2f * v2; float p2 = __expf(v2);
        float v3 = ss3 + sd; v3 = (v3 > 0.f) ? v3 : 0.2f * v3; float p3 = __expf(v3);
        den += p0 + p1 + p2 + p3;
        acc = fmaf(p0, w0, acc);
        acc = fmaf(p1, w1, acc);
        acc = fmaf(p2, w2, acc);
        acc = fmaf(p3, w3, acc);
    }
    for (; i < end; ++i) {
        int s = srcs[i];
        float ss = s_src[s * NH + hh];
        float w = __half2float(Wh[(long)s * NC + lane]);
        float v = ss + sd; v = (v > 0.f) ? v : 0.2f * v;
        float p = __expf(v);
        den += p;
        acc = fmaf(p, w, acc);
    }
    out[(long)wid * NC + lane] = acc / fmaxf(den, 1e-16f);
}

extern "C" void kernel_launch(void* const* d_in, const int* in_sizes, int n_in,
                              void* d_out, int out_size, void* d_ws, size_t ws_size,
                              hipStream_t stream)
{
    const float* h  = (const float*)d_in[0];
    const float* W  = (const float*)d_in[1];
    const float* a1 = (const float*)d_in[2];
    const float* a2 = (const float*)d_in[3];
    const int*  src = (const int*)d_in[4];
    const int*  dst = (const int*)d_in[5];
    float* out = (float*)d_out;

    const int N = in_sizes[0] / FIN;   // 50000
    const int E = in_sizes[4];         // 800000

    // workspace layout (16B-aligned chunks)
    char* wsb = (char*)d_ws;
    __half* Wh   = (__half*)wsb;                        wsb += (size_t)N * NC * 2;
    float* s_src = (float*)wsb;                         wsb += (size_t)N * NH * 4;
    float* s_dst = (float*)wsb;                         wsb += (size_t)N * NH * 4;
    int* row_off = (int*)wsb;                           wsb += (size_t)N * 4;
    int* cnt     = (int*)wsb;                           wsb += (size_t)N * 4;
    int* partials= (int*)wsb;                           wsb += (size_t)SCAN_BLK * 4;
    int* srcs    = (int*)wsb;                           wsb += (size_t)E * 4;

    const int nblk = (N + SCAN_BLK - 1) / SCAN_BLK;    // 196 <= 256

    hipMemsetAsync(cnt, 0, (size_t)N * 4, stream);

    int gemm_blocks = (N + 31) / 32;
    gemm_s_hist_kernel<<<gemm_blocks, 256, 0, stream>>>(
        h, W, a1, a2, dst, cnt, Wh, s_src, s_dst, N, E);

    scan1_kernel<<<nblk, SCAN_BLK, 0, stream>>>(cnt, row_off, partials, N);
    scan2_kernel<<<1, SCAN_BLK, 0, stream>>>(partials, nblk);
    scan3_kernel<<<nblk, SCAN_BLK, 0, stream>>>(row_off, partials, N);

    int e_blocks = (E + 255) / 256;
    fill_kernel<<<e_blocks, 256, 0, stream>>>(src, dst, row_off, srcs, E);

    int g_blocks = (N + 3) / 4;
    gather_kernel<<<g_blocks, 256, 0, stream>>>(srcs, row_off, s_src, s_dst, Wh, out, N);
}

// Round 4
// 148.335 us; speedup vs baseline: 10.2864x; 1.0733x over previous
//
#include <hip/hip_runtime.h>
#include <hip/hip_bf16.h>
#include <hip/hip_fp16.h>

// GAT fused layer for MI355X — round 4: MFMA bf16 projection GEMM.
//   memset cnt=0
//   K1 gemm_s_hist : Wh(fp16) = h @ W' via mfma_f32_16x16x32_bf16 (+ s epilogue + dst hist)
//   K2 scan1, K3 scan23 : exclusive scan cnt -> row_off
//   K4 fill        : CSR fill (atomicAdd on row_off; old value = slot)
//   K5 gather      : per dst-node wave, masked unroll-8, fp16 Wh gathers

#define FIN 128
#define NH 8
#define NO 8
#define NC 64
#define SCAN_BLK 256
#define GR 64   // gemm rows per block

typedef __attribute__((ext_vector_type(8))) short bf16x8;
typedef __attribute__((ext_vector_type(4))) float f32x4;

// f32 -> bf16 round-to-nearest-even (finite inputs only)
static __device__ __forceinline__ unsigned short f2bf(float f) {
    unsigned u = __float_as_uint(f);
    u += 0x7fff + ((u >> 16) & 1);
    return (unsigned short)(u >> 16);
}

__global__ __launch_bounds__(256) void gemm_s_hist_kernel(
    const float* __restrict__ h, const float* __restrict__ W,
    const float* __restrict__ a1, const float* __restrict__ a2,
    const int* __restrict__ dst, int* __restrict__ cnt,
    __half* __restrict__ Wh, float* __restrict__ s_src, float* __restrict__ s_dst,
    int N, int E)
{
    // XOR-swizzled bf16 tiles: byte ^= (row&7)<<4 spreads 256B-stride rows over banks
    __shared__ unsigned short hA[GR * FIN];   // 16 KB  [row][k]
    __shared__ unsigned short wB[NC * FIN];   // 16 KB  [c][k] (W column-major)
    const int tid = threadIdx.x;
    const int row0 = blockIdx.x * GR;

    // fused dst histogram (fire-and-forget int atomics, overlapped across blocks)
    for (long e = (long)blockIdx.x * 256 + tid; e < E; e += (long)gridDim.x * 256)
        atomicAdd(&cnt[dst[e]], 1);

    // stage hA: thread t -> row r=t>>2, k chunk (t&3)*32..+31  (8 x float4)
    {
        int r = tid >> 2;
        int c0 = (tid & 3) * 32;
        int n = row0 + r;
        const float4* hp = (const float4*)(h + (long)n * FIN + c0);
        char* base = (char*)hA + r * (FIN * 2);
        int sw = (r & 7) << 4;
#pragma unroll
        for (int j = 0; j < 8; ++j) {
            float4 v = (n < N) ? hp[j] : make_float4(0.f, 0.f, 0.f, 0.f);
            ushort4 b;
            b.x = f2bf(v.x); b.y = f2bf(v.y); b.z = f2bf(v.z); b.w = f2bf(v.w);
            int byte = (c0 + j * 4) * 2;
            *(ushort4*)(base + (byte ^ sw)) = b;
        }
    }
    // stage wB: linear coalesced read of W[8][128][8], scatter to [c][k] swizzled
    for (int i = tid; i < NH * FIN * NO; i += 256) {
        int hh = i >> 10;          // head
        int f  = (i >> 3) & 127;   // k
        int o  = i & 7;
        int c  = hh * 8 + o;
        unsigned short b = f2bf(W[i]);
        *(unsigned short*)((char*)wB + c * (FIN * 2) + ((f * 2) ^ ((c & 7) << 4))) = b;
    }
    __syncthreads();

    const int w    = tid >> 6;      // wave 0..3 -> rows w*16..w*16+15
    const int lane = tid & 63;
    const int l15  = lane & 15;
    const int lg   = lane >> 4;     // 0..3
    const int arow = w * 16 + l15;  // A-frag row (A: row=lane&15, k=(lane>>4)*8+j)

    f32x4 acc[4] = {{0,0,0,0},{0,0,0,0},{0,0,0,0},{0,0,0,0}};

    const char* hbase = (const char*)hA + arow * (FIN * 2);
    const int hsw = (arow & 7) << 4;
#pragma unroll
    for (int kk = 0; kk < 4; ++kk) {
        int kb = kk * 64 + lg * 16;   // byte offset of this lane's 8 bf16
        bf16x8 af = *(const bf16x8*)(hbase + (kb ^ hsw));
#pragma unroll
        for (int nt = 0; nt < 4; ++nt) {
            int c = nt * 16 + l15;    // B: col=lane&15, k=(lane>>4)*8+j
            bf16x8 bf = *(const bf16x8*)((const char*)wB + c * (FIN * 2) + (kb ^ ((c & 7) << 4)));
            acc[nt] = __builtin_amdgcn_mfma_f32_16x16x32_bf16(af, bf, acc[nt], 0, 0, 0);
        }
    }

    // epilogue: C/D layout col=lane&15, row=(lane>>4)*4+reg (m89-verified)
#pragma unroll
    for (int nt = 0; nt < 4; ++nt) {
        int col = nt * 16 + l15;
        float a1c = a1[col];
        float a2c = a2[col];
#pragma unroll
        for (int r = 0; r < 4; ++r) {
            int n = row0 + w * 16 + lg * 4 + r;
            float v = acc[nt][r];
            bool ok = (n < N);
            if (ok) Wh[(long)n * NC + col] = __float2half_rn(v);
            float ps = v * a1c, pd = v * a2c;
            ps += __shfl_xor(ps, 1); pd += __shfl_xor(pd, 1);
            ps += __shfl_xor(ps, 2); pd += __shfl_xor(pd, 2);
            ps += __shfl_xor(ps, 4); pd += __shfl_xor(pd, 4);
            if (ok && (col & 7) == 0) {
                s_src[n * NH + (col >> 3)] = ps;
                s_dst[n * NH + (col >> 3)] = pd;
            }
        }
    }
}

__global__ __launch_bounds__(256) void scan1_kernel(
    const int* __restrict__ cnt, int* __restrict__ row_off,
    int* __restrict__ partials, int N)
{
    __shared__ int sm[SCAN_BLK];
    int i = blockIdx.x * SCAN_BLK + threadIdx.x;
    int v = (i < N) ? cnt[i] : 0;
    sm[threadIdx.x] = v;
    __syncthreads();
    for (int off = 1; off < SCAN_BLK; off <<= 1) {
        int t = (threadIdx.x >= off) ? sm[threadIdx.x - off] : 0;
        __syncthreads();
        sm[threadIdx.x] += t;
        __syncthreads();
    }
    if (i < N) row_off[i] = sm[threadIdx.x] - v;   // exclusive within block
    if (threadIdx.x == SCAN_BLK - 1) partials[blockIdx.x] = sm[SCAN_BLK - 1];
}

// fused scan2+scan3: every block re-scans the partials in LDS, adds its prefix
__global__ __launch_bounds__(256) void scan23_kernel(
    int* __restrict__ row_off, const int* __restrict__ partials, int N, int nblk)
{
    __shared__ int sm[SCAN_BLK];
    int t = threadIdx.x;
    sm[t] = (t < nblk) ? partials[t] : 0;
    __syncthreads();
    for (int off = 1; off < SCAN_BLK; off <<= 1) {
        int v = (t >= off) ? sm[t - off] : 0;
        __syncthreads();
        sm[t] += v;
        __syncthreads();
    }
    int add = (blockIdx.x > 0) ? sm[blockIdx.x - 1] : 0;
    int i = blockIdx.x * SCAN_BLK + t;
    if (i < N) row_off[i] += add;
}

// CSR fill: atomicAdd on row_off itself; returned old value is the slot.
// Afterwards row_off[d] == exclusive_scan[d+1]; gather uses beg=row_off[d-1].
__global__ __launch_bounds__(256) void fill_kernel(
    const int* __restrict__ src, const int* __restrict__ dst,
    int* __restrict__ row_off, int* __restrict__ srcs, int E)
{
    int e = blockIdx.x * 256 + threadIdx.x;
    if (e >= E) return;
    int pos = atomicAdd(&row_off[dst[e]], 1);
    srcs[pos] = src[e];
}

__global__ __launch_bounds__(256) void gather_kernel(
    const int* __restrict__ srcs, const int* __restrict__ row_off,
    const float* __restrict__ s_src, const float* __restrict__ s_dst,
    const __half* __restrict__ Wh, float* __restrict__ out, int N)
{
    int wid = blockIdx.x * 4 + (threadIdx.x >> 6);   // one wave per dst node
    if (wid >= N) return;
    const int lane = threadIdx.x & 63;
    const int hh = lane >> 3;
    int beg = (wid == 0) ? 0 : row_off[wid - 1];
    int end = row_off[wid];
    float sd = s_dst[wid * NH + hh];
    float acc = 0.f, den = 0.f;
    // masked unroll-8: predicated tail folded in -> 8 gather chains in flight
    for (int i = beg; i < end; i += 8) {
#pragma unroll
        for (int k = 0; k < 8; ++k) {
            int idx = i + k;
            bool val = (idx < end);
            idx = val ? idx : beg;
            int s = srcs[idx];
            float ss = s_src[s * NH + hh];
            float wv = __half2float(Wh[(long)s * NC + lane]);
            float v = ss + sd;
            v = (v > 0.f) ? v : 0.2f * v;          // leaky_relu
            float p = __expf(v);                   // shift-invariant softmax, no max pass
            p = val ? p : 0.f;
            den += p;
            acc = fmaf(p, wv, acc);
        }
    }
    out[(long)wid * NC + lane] = acc / fmaxf(den, 1e-16f);
}

extern "C" void kernel_launch(void* const* d_in, const int* in_sizes, int n_in,
                              void* d_out, int out_size, void* d_ws, size_t ws_size,
                              hipStream_t stream)
{
    const float* h  = (const float*)d_in[0];
    const float* W  = (const float*)d_in[1];
    const float* a1 = (const float*)d_in[2];
    const float* a2 = (const float*)d_in[3];
    const int*  src = (const int*)d_in[4];
    const int*  dst = (const int*)d_in[5];
    float* out = (float*)d_out;

    const int N = in_sizes[0] / FIN;   // 50000
    const int E = in_sizes[4];         // 800000

    // workspace layout
    char* wsb = (char*)d_ws;
    __half* Wh   = (__half*)wsb;                        wsb += (size_t)N * NC * 2;
    float* s_src = (float*)wsb;                         wsb += (size_t)N * NH * 4;
    float* s_dst = (float*)wsb;                         wsb += (size_t)N * NH * 4;
    int* row_off = (int*)wsb;                           wsb += (size_t)N * 4;
    int* cnt     = (int*)wsb;                           wsb += (size_t)N * 4;
    int* partials= (int*)wsb;                           wsb += (size_t)SCAN_BLK * 4;
    int* srcs    = (int*)wsb;                           wsb += (size_t)E * 4;

    const int nblk = (N + SCAN_BLK - 1) / SCAN_BLK;    // 196 <= 256

    hipMemsetAsync(cnt, 0, (size_t)N * 4, stream);

    int gemm_blocks = (N + GR - 1) / GR;
    gemm_s_hist_kernel<<<gemm_blocks, 256, 0, stream>>>(
        h, W, a1, a2, dst, cnt, Wh, s_src, s_dst, N, E);

    scan1_kernel<<<nblk, SCAN_BLK, 0, stream>>>(cnt, row_off, partials, N);
    scan23_kernel<<<nblk, SCAN_BLK, 0, stream>>>(row_off, partials, N, nblk);

    int e_blocks = (E + 255) / 256;
    fill_kernel<<<e_blocks, 256, 0, stream>>>(src, dst, row_off, srcs, E);

    int g_blocks = (N + 3) / 4;
    gather_kernel<<<g_blocks, 256, 0, stream>>>(srcs, row_off, s_src, s_dst, Wh, out, N);
}

// Round 5
// 125.182 us; speedup vs baseline: 12.1889x; 1.1850x over previous
//
#include <hip/hip_runtime.h>
#include <hip/hip_bf16.h>
#include <hip/hip_fp16.h>

// GAT fused layer for MI355X — round 5: line-granular CSR build (no per-edge global atomics).
//   memset cnt=0
//   K1 gemm_s_hist : Wh(fp16) = h @ W' via mfma (+ s epilogue + fused dst hist)
//   K2 scan1, K3 scan23 : exclusive scan cnt -> row_off (+ bucket_cur seed, row_off[N]=E)
//   K4 bucketA     : edges -> 196 coarse buckets (packed u32), LDS-aggregated reservations
//   K5 bucketB     : per-bucket LDS counting sort -> srcs (u16), coalesced write
//   K6 gather      : per dst-node wave, masked unroll-8, fp16 Wh gathers

#define FIN 128
#define NH 8
#define NO 8
#define NC 64
#define SCAN_BLK 256
#define GR 64     // gemm rows per block
#define EPB 4096  // edges per bucketA workgroup
#define BCAP 8192 // max edges per coarse bucket (avg 4096, sigma ~64)

typedef __attribute__((ext_vector_type(8))) short bf16x8;
typedef __attribute__((ext_vector_type(4))) float f32x4;

static __device__ __forceinline__ unsigned short f2bf(float f) {
    unsigned u = __float_as_uint(f);
    u += 0x7fff + ((u >> 16) & 1);
    return (unsigned short)(u >> 16);
}

__global__ __launch_bounds__(256) void gemm_s_hist_kernel(
    const float* __restrict__ h, const float* __restrict__ W,
    const float* __restrict__ a1, const float* __restrict__ a2,
    const int* __restrict__ dst, int* __restrict__ cnt,
    __half* __restrict__ Wh, float* __restrict__ s_src, float* __restrict__ s_dst,
    int N, int E)
{
    __shared__ unsigned short hA[GR * FIN];   // 16 KB, XOR-swizzled
    __shared__ unsigned short wB[NC * FIN];   // 16 KB
    const int tid = threadIdx.x;
    const int row0 = blockIdx.x * GR;

    // fused dst histogram (fire-and-forget int atomics, overlapped with staging/MFMA)
    for (long e = (long)blockIdx.x * 256 + tid; e < E; e += (long)gridDim.x * 256)
        atomicAdd(&cnt[dst[e]], 1);

    {   // stage hA: row r=t>>2, k chunk (t&3)*32..+31
        int r = tid >> 2;
        int c0 = (tid & 3) * 32;
        int n = row0 + r;
        const float4* hp = (const float4*)(h + (long)n * FIN + c0);
        char* base = (char*)hA + r * (FIN * 2);
        int sw = (r & 7) << 4;
#pragma unroll
        for (int j = 0; j < 8; ++j) {
            float4 v = (n < N) ? hp[j] : make_float4(0.f, 0.f, 0.f, 0.f);
            ushort4 b;
            b.x = f2bf(v.x); b.y = f2bf(v.y); b.z = f2bf(v.z); b.w = f2bf(v.w);
            int byte = (c0 + j * 4) * 2;
            *(ushort4*)(base + (byte ^ sw)) = b;
        }
    }
    for (int i = tid; i < NH * FIN * NO; i += 256) {
        int hh = i >> 10, f = (i >> 3) & 127, o = i & 7;
        int c = hh * 8 + o;
        *(unsigned short*)((char*)wB + c * (FIN * 2) + ((f * 2) ^ ((c & 7) << 4))) = f2bf(W[i]);
    }
    __syncthreads();

    const int w    = tid >> 6;
    const int lane = tid & 63;
    const int l15  = lane & 15;
    const int lg   = lane >> 4;
    const int arow = w * 16 + l15;

    f32x4 acc[4] = {{0,0,0,0},{0,0,0,0},{0,0,0,0},{0,0,0,0}};
    const char* hbase = (const char*)hA + arow * (FIN * 2);
    const int hsw = (arow & 7) << 4;
#pragma unroll
    for (int kk = 0; kk < 4; ++kk) {
        int kb = kk * 64 + lg * 16;
        bf16x8 af = *(const bf16x8*)(hbase + (kb ^ hsw));
#pragma unroll
        for (int nt = 0; nt < 4; ++nt) {
            int c = nt * 16 + l15;
            bf16x8 bf = *(const bf16x8*)((const char*)wB + c * (FIN * 2) + (kb ^ ((c & 7) << 4)));
            acc[nt] = __builtin_amdgcn_mfma_f32_16x16x32_bf16(af, bf, acc[nt], 0, 0, 0);
        }
    }

#pragma unroll
    for (int nt = 0; nt < 4; ++nt) {
        int col = nt * 16 + l15;
        float a1c = a1[col];
        float a2c = a2[col];
#pragma unroll
        for (int r = 0; r < 4; ++r) {
            int n = row0 + w * 16 + lg * 4 + r;
            float v = acc[nt][r];
            bool ok = (n < N);
            if (ok) Wh[(long)n * NC + col] = __float2half_rn(v);
            float ps = v * a1c, pd = v * a2c;
            ps += __shfl_xor(ps, 1); pd += __shfl_xor(pd, 1);
            ps += __shfl_xor(ps, 2); pd += __shfl_xor(pd, 2);
            ps += __shfl_xor(ps, 4); pd += __shfl_xor(pd, 4);
            if (ok && (col & 7) == 0) {
                s_src[n * NH + (col >> 3)] = ps;
                s_dst[n * NH + (col >> 3)] = pd;
            }
        }
    }
}

__global__ __launch_bounds__(256) void scan1_kernel(
    const int* __restrict__ cnt, int* __restrict__ row_off,
    int* __restrict__ partials, int N)
{
    __shared__ int sm[SCAN_BLK];
    int i = blockIdx.x * SCAN_BLK + threadIdx.x;
    int v = (i < N) ? cnt[i] : 0;
    sm[threadIdx.x] = v;
    __syncthreads();
    for (int off = 1; off < SCAN_BLK; off <<= 1) {
        int t = (threadIdx.x >= off) ? sm[threadIdx.x - off] : 0;
        __syncthreads();
        sm[threadIdx.x] += t;
        __syncthreads();
    }
    if (i < N) row_off[i] = sm[threadIdx.x] - v;   // exclusive within block
    if (threadIdx.x == SCAN_BLK - 1) partials[blockIdx.x] = sm[SCAN_BLK - 1];
}

// fused scan2+scan3 + bucket_cur seed + row_off[N]=E
__global__ __launch_bounds__(256) void scan23_kernel(
    int* __restrict__ row_off, const int* __restrict__ partials,
    int* __restrict__ bucket_cur, int N, int nblk, int E)
{
    __shared__ int sm[SCAN_BLK];
    int t = threadIdx.x;
    sm[t] = (t < nblk) ? partials[t] : 0;
    __syncthreads();
    for (int off = 1; off < SCAN_BLK; off <<= 1) {
        int v = (t >= off) ? sm[t - off] : 0;
        __syncthreads();
        sm[t] += v;
        __syncthreads();
    }
    int add = (blockIdx.x > 0) ? sm[blockIdx.x - 1] : 0;
    int i = blockIdx.x * SCAN_BLK + t;
    if (i < N) {
        int val = row_off[i] + add;
        row_off[i] = val;
        if (t == 0) bucket_cur[blockIdx.x] = val;   // SCAN_BLK == bucket width == 256
    }
    if (blockIdx.x == 0 && t == 0) row_off[N] = E;
}

// Pass A: coarse bucket scatter. One global atomic per (WG, bucket).
__global__ __launch_bounds__(256) void bucketA_kernel(
    const int* __restrict__ src, const int* __restrict__ dst,
    int* __restrict__ bucket_cur, unsigned* __restrict__ packed, int E)
{
    __shared__ int cnt_l[256];
    __shared__ int base_l[256];
    const int t = threadIdx.x;
    const int e0 = blockIdx.x * EPB;
    cnt_l[t] = 0;
    __syncthreads();

    int br[16];        // (bucket<<16) | local rank   (static-indexed)
    unsigned pk[16];   // (dst&255)<<16 | src
#pragma unroll
    for (int j = 0; j < 16; ++j) {
        int e = e0 + j * 256 + t;
        bool ok = (e < E);
        int d = ok ? dst[e] : 0;
        int s = ok ? src[e] : 0;
        int b = d >> 8;
        int r = ok ? atomicAdd(&cnt_l[b], 1) : 0;
        br[j] = ok ? ((b << 16) | r) : -1;
        pk[j] = ((unsigned)(d & 255) << 16) | (unsigned)s;
    }
    __syncthreads();
    if (cnt_l[t] > 0) base_l[t] = atomicAdd(&bucket_cur[t], cnt_l[t]);
    __syncthreads();
#pragma unroll
    for (int j = 0; j < 16; ++j) {
        if (br[j] >= 0)
            packed[base_l[br[j] >> 16] + (br[j] & 0xFFFF)] = pk[j];
    }
}

// Pass B: per-bucket counting sort in LDS; coalesced u16 output.
__global__ __launch_bounds__(256) void bucketB_kernel(
    const unsigned* __restrict__ packed, const int* __restrict__ row_off,
    unsigned short* __restrict__ srcs, int N)
{
    __shared__ int bins[256];
    __shared__ int scan_s[256];
    __shared__ unsigned short outb[BCAP];
    const int t = threadIdx.x;
    const int d0 = blockIdx.x << 8;
    const int g0 = row_off[d0];
    const int g1 = row_off[min(d0 + 256, N)];
    const int cnt = g1 - g0;

    bins[t] = 0;
    __syncthreads();
    for (int i = t; i < cnt; i += 256)
        atomicAdd(&bins[packed[g0 + i] >> 16], 1);
    __syncthreads();
    int v = bins[t];
    scan_s[t] = v;
    __syncthreads();
    for (int off = 1; off < 256; off <<= 1) {
        int u = (t >= off) ? scan_s[t - off] : 0;
        __syncthreads();
        scan_s[t] += u;
        __syncthreads();
    }
    bins[t] = scan_s[t] - v;   // exclusive scan -> running cursor
    __syncthreads();
    for (int i = t; i < cnt; i += 256) {
        unsigned p = packed[g0 + i];
        int pos = atomicAdd(&bins[p >> 16], 1);
        outb[pos] = (unsigned short)(p & 0xFFFF);
    }
    __syncthreads();
    for (int i = t; i < cnt; i += 256)
        srcs[g0 + i] = outb[i];
}

__global__ __launch_bounds__(256) void gather_kernel(
    const unsigned short* __restrict__ srcs, const int* __restrict__ row_off,
    const float* __restrict__ s_src, const float* __restrict__ s_dst,
    const __half* __restrict__ Wh, float* __restrict__ out, int N)
{
    int wid = blockIdx.x * 4 + (threadIdx.x >> 6);   // one wave per dst node
    if (wid >= N) return;
    const int lane = threadIdx.x & 63;
    const int hh = lane >> 3;
    int beg = row_off[wid];
    int end = row_off[wid + 1];
    float sd = s_dst[wid * NH + hh];
    float acc = 0.f, den = 0.f;
    for (int i = beg; i < end; i += 8) {
#pragma unroll
        for (int k = 0; k < 8; ++k) {
            int idx = i + k;
            bool val = (idx < end);
            idx = val ? idx : beg;
            int s = srcs[idx];
            float ss = s_src[s * NH + hh];
            float wv = __half2float(Wh[(long)s * NC + lane]);
            float x = ss + sd;
            x = (x > 0.f) ? x : 0.2f * x;          // leaky_relu
            float p = __expf(x);                   // shift-invariant softmax, no max pass
            p = val ? p : 0.f;
            den += p;
            acc = fmaf(p, wv, acc);
        }
    }
    out[(long)wid * NC + lane] = acc / fmaxf(den, 1e-16f);
}

extern "C" void kernel_launch(void* const* d_in, const int* in_sizes, int n_in,
                              void* d_out, int out_size, void* d_ws, size_t ws_size,
                              hipStream_t stream)
{
    const float* h  = (const float*)d_in[0];
    const float* W  = (const float*)d_in[1];
    const float* a1 = (const float*)d_in[2];
    const float* a2 = (const float*)d_in[3];
    const int*  src = (const int*)d_in[4];
    const int*  dst = (const int*)d_in[5];
    float* out = (float*)d_out;

    const int N = in_sizes[0] / FIN;   // 50000
    const int E = in_sizes[4];         // 800000

    // workspace layout
    char* wsb = (char*)d_ws;
    __half* Wh        = (__half*)wsb;          wsb += (size_t)N * NC * 2;
    float* s_src      = (float*)wsb;           wsb += (size_t)N * NH * 4;
    float* s_dst      = (float*)wsb;           wsb += (size_t)N * NH * 4;
    int* row_off      = (int*)wsb;             wsb += (size_t)(N + 1) * 4;
    int* cnt          = (int*)wsb;             wsb += (size_t)N * 4;
    int* partials     = (int*)wsb;             wsb += (size_t)SCAN_BLK * 4;
    int* bucket_cur   = (int*)wsb;             wsb += (size_t)256 * 4;
    unsigned* packed  = (unsigned*)wsb;        wsb += (size_t)E * 4;
    unsigned short* srcs = (unsigned short*)wsb; wsb += (size_t)E * 2;

    const int nblk = (N + SCAN_BLK - 1) / SCAN_BLK;    // 196 (== #buckets)

    hipMemsetAsync(cnt, 0, (size_t)N * 4, stream);

    int gemm_blocks = (N + GR - 1) / GR;
    gemm_s_hist_kernel<<<gemm_blocks, 256, 0, stream>>>(
        h, W, a1, a2, dst, cnt, Wh, s_src, s_dst, N, E);

    scan1_kernel<<<nblk, SCAN_BLK, 0, stream>>>(cnt, row_off, partials, N);
    scan23_kernel<<<nblk, SCAN_BLK, 0, stream>>>(row_off, partials, bucket_cur, N, nblk, E);

    int a_blocks = (E + EPB - 1) / EPB;
    bucketA_kernel<<<a_blocks, 256, 0, stream>>>(src, dst, bucket_cur, packed, E);
    bucketB_kernel<<<nblk, 256, 0, stream>>>(packed, row_off, srcs, N);

    int g_blocks = (N + 3) / 4;
    gather_kernel<<<g_blocks, 256, 0, stream>>>(srcs, row_off, s_src, s_dst, Wh, out, N);
}

// Round 6
// 100.665 us; speedup vs baseline: 15.1575x; 1.2436x over previous
//
#include <hip/hip_runtime.h>
#include <hip/hip_bf16.h>
#include <hip/hip_fp16.h>

// GAT fused layer for MI355X — round 6: histogram-free CSR build.
//   memset bcnt=0 (1 KB)
//   K1 gemm_s_bucket : Wh(fp16) = h @ W' via mfma (+ s epilogue + fused coarse-bucket scatter)
//   K2 bucket_scan   : exclusive scan of bcnt[196] -> bucket_base (1 WG)
//   K3 bucketB       : per-bucket LDS counting sort -> srcs (u16) + row_off (derived, coalesced)
//   K4 gather        : per dst-node wave, masked unroll-16, fp16 Wh gathers

#define FIN 128
#define NH 8
#define NO 8
#define NC 64
#define GR 64     // gemm rows per block
#define BCAP 8192 // slots per coarse bucket (mean 4096, ~64 sigma headroom)

typedef __attribute__((ext_vector_type(8))) short bf16x8;
typedef __attribute__((ext_vector_type(4))) float f32x4;

static __device__ __forceinline__ unsigned short f2bf(float f) {
    unsigned u = __float_as_uint(f);
    u += 0x7fff + ((u >> 16) & 1);
    return (unsigned short)(u >> 16);
}

__global__ __launch_bounds__(256) void gemm_s_bucket_kernel(
    const float* __restrict__ h, const float* __restrict__ W,
    const float* __restrict__ a1, const float* __restrict__ a2,
    const int* __restrict__ src, const int* __restrict__ dst,
    int* __restrict__ bcnt, unsigned* __restrict__ packed,
    __half* __restrict__ Wh, float* __restrict__ s_src, float* __restrict__ s_dst,
    int N, int E)
{
    __shared__ unsigned short hA[GR * FIN];   // 16 KB, XOR-swizzled
    __shared__ unsigned short wB[NC * FIN];   // 16 KB
    __shared__ int cnt_l[256];
    __shared__ int base_l[256];
    const int tid = threadIdx.x;
    const int row0 = blockIdx.x * GR;

    // ---- fused coarse-bucket edge scatter (replaces the 800K-atomic histogram) ----
    // bucket = dst>>8; region = packed[b*BCAP ..]; one global atomic per (WG,bucket).
    for (long base = (long)blockIdx.x * 1024; base < E; base += (long)gridDim.x * 1024) {
        cnt_l[tid] = 0;
        __syncthreads();
        int br[4]; unsigned pk[4];
#pragma unroll
        for (int j = 0; j < 4; ++j) {
            long e = base + j * 256 + tid;
            bool ok = (e < E);
            int d = ok ? dst[e] : 0;
            int s = ok ? src[e] : 0;
            int b = d >> 8;
            int r = ok ? atomicAdd(&cnt_l[b], 1) : 0;
            br[j] = ok ? ((b << 16) | r) : -1;
            pk[j] = ((unsigned)(d & 255) << 16) | (unsigned)s;   // src < 65536
        }
        __syncthreads();
        if (cnt_l[tid] > 0) base_l[tid] = atomicAdd(&bcnt[tid], cnt_l[tid]);
        __syncthreads();
#pragma unroll
        for (int j = 0; j < 4; ++j) {
            if (br[j] >= 0) {
                int b = br[j] >> 16, r = br[j] & 0xFFFF;
                packed[(long)b * BCAP + base_l[b] + r] = pk[j];
            }
        }
        __syncthreads();
    }

    // ---- stage hA: row r=t>>2, k chunk (t&3)*32..+31, byte ^= (row&7)<<4 ----
    {
        int r = tid >> 2;
        int c0 = (tid & 3) * 32;
        int n = row0 + r;
        const float4* hp = (const float4*)(h + (long)n * FIN + c0);
        char* basep = (char*)hA + r * (FIN * 2);
        int sw = (r & 7) << 4;
#pragma unroll
        for (int j = 0; j < 8; ++j) {
            float4 v = (n < N) ? hp[j] : make_float4(0.f, 0.f, 0.f, 0.f);
            ushort4 b;
            b.x = f2bf(v.x); b.y = f2bf(v.y); b.z = f2bf(v.z); b.w = f2bf(v.w);
            int byte = (c0 + j * 4) * 2;
            *(ushort4*)(basep + (byte ^ sw)) = b;
        }
    }
    for (int i = tid; i < NH * FIN * NO; i += 256) {
        int hh = i >> 10, f = (i >> 3) & 127, o = i & 7;
        int c = hh * 8 + o;
        *(unsigned short*)((char*)wB + c * (FIN * 2) + ((f * 2) ^ ((c & 7) << 4))) = f2bf(W[i]);
    }
    __syncthreads();

    const int w    = tid >> 6;
    const int lane = tid & 63;
    const int l15  = lane & 15;
    const int lg   = lane >> 4;
    const int arow = w * 16 + l15;

    f32x4 acc[4] = {{0,0,0,0},{0,0,0,0},{0,0,0,0},{0,0,0,0}};
    const char* hbase = (const char*)hA + arow * (FIN * 2);
    const int hsw = (arow & 7) << 4;
#pragma unroll
    for (int kk = 0; kk < 4; ++kk) {
        int kb = kk * 64 + lg * 16;
        bf16x8 af = *(const bf16x8*)(hbase + (kb ^ hsw));
#pragma unroll
        for (int nt = 0; nt < 4; ++nt) {
            int c = nt * 16 + l15;
            bf16x8 bf = *(const bf16x8*)((const char*)wB + c * (FIN * 2) + (kb ^ ((c & 7) << 4)));
            acc[nt] = __builtin_amdgcn_mfma_f32_16x16x32_bf16(af, bf, acc[nt], 0, 0, 0);
        }
    }

    // epilogue: C/D layout col=lane&15, row=(lane>>4)*4+reg
#pragma unroll
    for (int nt = 0; nt < 4; ++nt) {
        int col = nt * 16 + l15;
        float a1c = a1[col];
        float a2c = a2[col];
#pragma unroll
        for (int r = 0; r < 4; ++r) {
            int n = row0 + w * 16 + lg * 4 + r;
            float v = acc[nt][r];
            bool ok = (n < N);
            if (ok) Wh[(long)n * NC + col] = __float2half_rn(v);
            float ps = v * a1c, pd = v * a2c;
            ps += __shfl_xor(ps, 1); pd += __shfl_xor(pd, 1);
            ps += __shfl_xor(ps, 2); pd += __shfl_xor(pd, 2);
            ps += __shfl_xor(ps, 4); pd += __shfl_xor(pd, 4);
            if (ok && (col & 7) == 0) {
                s_src[n * NH + (col >> 3)] = ps;
                s_dst[n * NH + (col >> 3)] = pd;
            }
        }
    }
}

// exclusive scan of bcnt[0..nb) -> bucket_base  (single workgroup)
__global__ __launch_bounds__(256) void bucket_scan_kernel(
    const int* __restrict__ bcnt, int* __restrict__ bucket_base, int nb)
{
    __shared__ int sm[256];
    int t = threadIdx.x;
    int v = (t < nb) ? bcnt[t] : 0;
    sm[t] = v;
    __syncthreads();
    for (int off = 1; off < 256; off <<= 1) {
        int u = (t >= off) ? sm[t - off] : 0;
        __syncthreads();
        sm[t] += u;
        __syncthreads();
    }
    bucket_base[t] = sm[t] - v;   // exclusive
}

// Per-bucket counting sort: bins -> local scan -> row_off (coalesced) + sorted u16 srcs.
__global__ __launch_bounds__(256) void bucketB_kernel(
    const unsigned* __restrict__ packed, const int* __restrict__ bcnt,
    const int* __restrict__ bucket_base, int* __restrict__ row_off,
    unsigned short* __restrict__ srcs, int N, int E, int nb)
{
    __shared__ int bins[256];
    __shared__ int scan_s[256];
    __shared__ unsigned short outb[BCAP];
    const int t = threadIdx.x;
    const int b = blockIdx.x;
    const int d0 = b << 8;
    const int g0 = bucket_base[b];
    const int cnt = bcnt[b];
    const unsigned* pin = packed + (long)b * BCAP;

    bins[t] = 0;
    __syncthreads();
    for (int i = t; i < cnt; i += 256)
        atomicAdd(&bins[pin[i] >> 16], 1);
    __syncthreads();
    int v = bins[t];
    scan_s[t] = v;
    __syncthreads();
    for (int off = 1; off < 256; off <<= 1) {
        int u = (t >= off) ? scan_s[t - off] : 0;
        __syncthreads();
        scan_s[t] += u;
        __syncthreads();
    }
    if (d0 + t < N) row_off[d0 + t] = g0 + scan_s[t] - v;   // exclusive
    if (b == nb - 1 && t == 0) row_off[N] = E;
    bins[t] = scan_s[t] - v;   // running cursor
    __syncthreads();
    for (int i = t; i < cnt; i += 256) {
        unsigned p = pin[i];
        int pos = atomicAdd(&bins[p >> 16], 1);
        outb[pos] = (unsigned short)(p & 0xFFFF);
    }
    __syncthreads();
    for (int i = t; i < cnt; i += 256)
        srcs[g0 + i] = outb[i];
}

__global__ __launch_bounds__(256) void gather_kernel(
    const unsigned short* __restrict__ srcs, const int* __restrict__ row_off,
    const float* __restrict__ s_src, const float* __restrict__ s_dst,
    const __half* __restrict__ Wh, float* __restrict__ out, int N)
{
    int wid = blockIdx.x * 4 + (threadIdx.x >> 6);   // one wave per dst node
    if (wid >= N) return;
    const int lane = threadIdx.x & 63;
    const int hh = lane >> 3;
    int beg = row_off[wid];
    int end = row_off[wid + 1];
    float sd = s_dst[wid * NH + hh];
    float acc = 0.f, den = 0.f;
    for (int i = beg; i < end; i += 16) {
#pragma unroll
        for (int k = 0; k < 16; ++k) {
            int idx = i + k;
            bool val = (idx < end);
            idx = val ? idx : beg;
            int s = srcs[idx];
            float ss = s_src[s * NH + hh];
            float wv = __half2float(Wh[(long)s * NC + lane]);
            float x = ss + sd;
            x = (x > 0.f) ? x : 0.2f * x;          // leaky_relu
            float p = __expf(x);                   // shift-invariant softmax, no max pass
            p = val ? p : 0.f;
            den += p;
            acc = fmaf(p, wv, acc);
        }
    }
    out[(long)wid * NC + lane] = acc / fmaxf(den, 1e-16f);
}

extern "C" void kernel_launch(void* const* d_in, const int* in_sizes, int n_in,
                              void* d_out, int out_size, void* d_ws, size_t ws_size,
                              hipStream_t stream)
{
    const float* h  = (const float*)d_in[0];
    const float* W  = (const float*)d_in[1];
    const float* a1 = (const float*)d_in[2];
    const float* a2 = (const float*)d_in[3];
    const int*  src = (const int*)d_in[4];
    const int*  dst = (const int*)d_in[5];
    float* out = (float*)d_out;

    const int N = in_sizes[0] / FIN;   // 50000
    const int E = in_sizes[4];         // 800000
    const int nb = (N + 255) >> 8;     // 196 coarse buckets

    // workspace layout (~17.8 MB; round-2 used 19.6 MB successfully)
    char* wsb = (char*)d_ws;
    __half* Wh         = (__half*)wsb;           wsb += (size_t)N * NC * 2;
    float* s_src       = (float*)wsb;            wsb += (size_t)N * NH * 4;
    float* s_dst       = (float*)wsb;            wsb += (size_t)N * NH * 4;
    int* row_off       = (int*)wsb;              wsb += (size_t)(N + 1) * 4;
    int* bcnt          = (int*)wsb;              wsb += (size_t)256 * 4;
    int* bucket_base   = (int*)wsb;              wsb += (size_t)256 * 4;
    unsigned* packed   = (unsigned*)wsb;         wsb += (size_t)nb * BCAP * 4;
    unsigned short* srcs = (unsigned short*)wsb; wsb += (size_t)E * 2;

    hipMemsetAsync(bcnt, 0, 256 * 4, stream);

    int gemm_blocks = (N + GR - 1) / GR;
    gemm_s_bucket_kernel<<<gemm_blocks, 256, 0, stream>>>(
        h, W, a1, a2, src, dst, bcnt, packed, Wh, s_src, s_dst, N, E);

    bucket_scan_kernel<<<1, 256, 0, stream>>>(bcnt, bucket_base, nb);
    bucketB_kernel<<<nb, 256, 0, stream>>>(packed, bcnt, bucket_base, row_off, srcs, N, E, nb);

    int g_blocks = (N + 3) / 4;
    gather_kernel<<<g_blocks, 256, 0, stream>>>(srcs, row_off, s_src, s_dst, Wh, out, N);
}

// Round 7
// 81.939 us; speedup vs baseline: 18.6215x; 1.2285x over previous
//
#include <hip/hip_runtime.h>
#include <hip/hip_bf16.h>
#include <hip/hip_fp16.h>

// GAT fused layer for MI355X — round 7: scatter as concurrent tail blocks.
//   memset bcnt=0 (1 KB)
//   K1 gemm_s_scat : blocks [0,782): Wh(fp16) = h @ W' via mfma (+ s epilogue)
//                    blocks [782,978): coarse-bucket edge scatter (4096 edges each,
//                    LDS-aggregated reservations -> 38K global atomics, depth 196/address)
//   K2 bucketB     : per-bucket LDS counting sort (+ inline bcnt scan) -> srcs(u16) + row_off
//   K3 gather      : per dst-node wave, masked unroll-16, dual accumulators

#define FIN 128
#define NH 8
#define NO 8
#define NC 64
#define GR 64     // gemm rows per block
#define EPB 4096  // edges per scatter block
#define BCAP 8192 // slots per coarse bucket (mean ~4082, sigma ~64)

typedef __attribute__((ext_vector_type(8))) short bf16x8;
typedef __attribute__((ext_vector_type(4))) float f32x4;

static __device__ __forceinline__ unsigned short f2bf(float f) {
    unsigned u = __float_as_uint(f);
    u += 0x7fff + ((u >> 16) & 1);
    return (unsigned short)(u >> 16);
}

__global__ __launch_bounds__(256) void gemm_s_scat_kernel(
    const float* __restrict__ h, const float* __restrict__ W,
    const float* __restrict__ a1, const float* __restrict__ a2,
    const int* __restrict__ src, const int* __restrict__ dst,
    int* __restrict__ bcnt, unsigned* __restrict__ packed,
    __half* __restrict__ Wh, float* __restrict__ s_src, float* __restrict__ s_dst,
    int N, int E, int gemm_blocks)
{
    __shared__ unsigned short hA[GR * FIN];   // 16 KB (scatter blocks alias counters here)
    __shared__ unsigned short wB[NC * FIN];   // 16 KB
    const int tid = threadIdx.x;

    if (blockIdx.x >= gemm_blocks) {
        // ---------------- scatter block: 4096 edges -> coarse buckets ----------------
        int* cnt_l  = (int*)hA;         // [256]
        int* base_l = cnt_l + 256;      // [256]
        const long e0 = (long)(blockIdx.x - gemm_blocks) * EPB;
        cnt_l[tid] = 0;
        __syncthreads();
        int br[16];        // (bucket<<16) | local rank
        unsigned pk[16];   // (dst&255)<<16 | src
#pragma unroll
        for (int j = 0; j < 16; ++j) {
            long e = e0 + j * 256 + tid;
            bool ok = (e < E);
            int d = ok ? dst[e] : 0;
            int s = ok ? src[e] : 0;
            int b = d >> 8;
            int r = ok ? atomicAdd(&cnt_l[b], 1) : 0;
            br[j] = ok ? ((b << 16) | r) : -1;
            pk[j] = ((unsigned)(d & 255) << 16) | (unsigned)s;   // src < 65536
        }
        __syncthreads();
        if (cnt_l[tid] > 0) base_l[tid] = atomicAdd(&bcnt[tid], cnt_l[tid]);
        __syncthreads();
#pragma unroll
        for (int j = 0; j < 16; ++j) {
            if (br[j] >= 0) {
                int b = br[j] >> 16, r = br[j] & 0xFFFF;
                packed[(long)b * BCAP + base_l[b] + r] = pk[j];
            }
        }
        return;
    }

    // ---------------- gemm block ----------------
    const int row0 = blockIdx.x * GR;
    {   // stage hA: row r=t>>2, k chunk (t&3)*32..+31, byte ^= (row&7)<<4
        int r = tid >> 2;
        int c0 = (tid & 3) * 32;
        int n = row0 + r;
        const float4* hp = (const float4*)(h + (long)n * FIN + c0);
        char* basep = (char*)hA + r * (FIN * 2);
        int sw = (r & 7) << 4;
#pragma unroll
        for (int j = 0; j < 8; ++j) {
            float4 v = (n < N) ? hp[j] : make_float4(0.f, 0.f, 0.f, 0.f);
            ushort4 b;
            b.x = f2bf(v.x); b.y = f2bf(v.y); b.z = f2bf(v.z); b.w = f2bf(v.w);
            int byte = (c0 + j * 4) * 2;
            *(ushort4*)(basep + (byte ^ sw)) = b;
        }
    }
    for (int i = tid; i < NH * FIN * NO; i += 256) {
        int hh = i >> 10, f = (i >> 3) & 127, o = i & 7;
        int c = hh * 8 + o;
        *(unsigned short*)((char*)wB + c * (FIN * 2) + ((f * 2) ^ ((c & 7) << 4))) = f2bf(W[i]);
    }
    __syncthreads();

    const int w    = tid >> 6;
    const int lane = tid & 63;
    const int l15  = lane & 15;
    const int lg   = lane >> 4;
    const int arow = w * 16 + l15;

    f32x4 acc[4] = {{0,0,0,0},{0,0,0,0},{0,0,0,0},{0,0,0,0}};
    const char* hbase = (const char*)hA + arow * (FIN * 2);
    const int hsw = (arow & 7) << 4;
#pragma unroll
    for (int kk = 0; kk < 4; ++kk) {
        int kb = kk * 64 + lg * 16;
        bf16x8 af = *(const bf16x8*)(hbase + (kb ^ hsw));
#pragma unroll
        for (int nt = 0; nt < 4; ++nt) {
            int c = nt * 16 + l15;
            bf16x8 bf = *(const bf16x8*)((const char*)wB + c * (FIN * 2) + (kb ^ ((c & 7) << 4)));
            acc[nt] = __builtin_amdgcn_mfma_f32_16x16x32_bf16(af, bf, acc[nt], 0, 0, 0);
        }
    }

    // epilogue: C/D layout col=lane&15, row=(lane>>4)*4+reg
#pragma unroll
    for (int nt = 0; nt < 4; ++nt) {
        int col = nt * 16 + l15;
        float a1c = a1[col];
        float a2c = a2[col];
#pragma unroll
        for (int r = 0; r < 4; ++r) {
            int n = row0 + w * 16 + lg * 4 + r;
            float v = acc[nt][r];
            bool ok = (n < N);
            if (ok) Wh[(long)n * NC + col] = __float2half_rn(v);
            float ps = v * a1c, pd = v * a2c;
            ps += __shfl_xor(ps, 1); pd += __shfl_xor(pd, 1);
            ps += __shfl_xor(ps, 2); pd += __shfl_xor(pd, 2);
            ps += __shfl_xor(ps, 4); pd += __shfl_xor(pd, 4);
            if (ok && (col & 7) == 0) {
                s_src[n * NH + (col >> 3)] = ps;
                s_dst[n * NH + (col >> 3)] = pd;
            }
        }
    }
}

// Per-bucket counting sort (+ inline exclusive scan of bcnt for the global base).
__global__ __launch_bounds__(256) void bucketB_kernel(
    const unsigned* __restrict__ packed, const int* __restrict__ bcnt,
    int* __restrict__ row_off, unsigned short* __restrict__ srcs,
    int N, int E, int nb)
{
    __shared__ int bins[256];
    __shared__ int scan_s[256];
    __shared__ int g0s;
    __shared__ unsigned short outb[BCAP];
    const int t = threadIdx.x;
    const int b = blockIdx.x;
    const int d0 = b << 8;
    const unsigned* pin = packed + (long)b * BCAP;

    // inline scan of bcnt -> this bucket's global base
    int v2 = (t < nb) ? bcnt[t] : 0;
    scan_s[t] = v2;
    __syncthreads();
    for (int off = 1; off < 256; off <<= 1) {
        int u = (t >= off) ? scan_s[t - off] : 0;
        __syncthreads();
        scan_s[t] += u;
        __syncthreads();
    }
    if (t == b) g0s = scan_s[t] - v2;   // exclusive prefix for bucket b
    bins[t] = 0;
    __syncthreads();
    const int g0 = g0s;
    const int cnt = bcnt[b];

    for (int i = t; i < cnt; i += 256)
        atomicAdd(&bins[pin[i] >> 16], 1);
    __syncthreads();
    int v = bins[t];
    scan_s[t] = v;
    __syncthreads();
    for (int off = 1; off < 256; off <<= 1) {
        int u = (t >= off) ? scan_s[t - off] : 0;
        __syncthreads();
        scan_s[t] += u;
        __syncthreads();
    }
    if (d0 + t < N) row_off[d0 + t] = g0 + scan_s[t] - v;   // exclusive
    if (b == nb - 1 && t == 0) row_off[N] = E;
    bins[t] = scan_s[t] - v;   // running cursor
    __syncthreads();
    for (int i = t; i < cnt; i += 256) {
        unsigned p = pin[i];
        int pos = atomicAdd(&bins[p >> 16], 1);
        outb[pos] = (unsigned short)(p & 0xFFFF);
    }
    __syncthreads();
    for (int i = t; i < cnt; i += 256)
        srcs[g0 + i] = outb[i];
}

__global__ __launch_bounds__(256) void gather_kernel(
    const unsigned short* __restrict__ srcs, const int* __restrict__ row_off,
    const float* __restrict__ s_src, const float* __restrict__ s_dst,
    const __half* __restrict__ Wh, float* __restrict__ out, int N)
{
    int wid = blockIdx.x * 4 + (threadIdx.x >> 6);   // one wave per dst node
    if (wid >= N) return;
    const int lane = threadIdx.x & 63;
    const int hh = lane >> 3;
    int beg = row_off[wid];
    int end = row_off[wid + 1];
    float sd = s_dst[wid * NH + hh];
    float acc0 = 0.f, den0 = 0.f, acc1 = 0.f, den1 = 0.f;
    for (int i = beg; i < end; i += 16) {
#pragma unroll
        for (int k = 0; k < 16; ++k) {
            int idx = i + k;
            bool val = (idx < end);
            idx = val ? idx : beg;
            int s = srcs[idx];
            float ss = s_src[s * NH + hh];
            float wv = __half2float(Wh[(long)s * NC + lane]);
            float x = ss + sd;
            x = (x > 0.f) ? x : 0.2f * x;          // leaky_relu
            float p = __expf(x);                   // shift-invariant softmax, no max pass
            p = val ? p : 0.f;
            if (k & 1) { den1 += p; acc1 = fmaf(p, wv, acc1); }
            else       { den0 += p; acc0 = fmaf(p, wv, acc0); }
        }
    }
    float acc = acc0 + acc1, den = den0 + den1;
    out[(long)wid * NC + lane] = acc / fmaxf(den, 1e-16f);
}

extern "C" void kernel_launch(void* const* d_in, const int* in_sizes, int n_in,
                              void* d_out, int out_size, void* d_ws, size_t ws_size,
                              hipStream_t stream)
{
    const float* h  = (const float*)d_in[0];
    const float* W  = (const float*)d_in[1];
    const float* a1 = (const float*)d_in[2];
    const float* a2 = (const float*)d_in[3];
    const int*  src = (const int*)d_in[4];
    const int*  dst = (const int*)d_in[5];
    float* out = (float*)d_out;

    const int N = in_sizes[0] / FIN;   // 50000
    const int E = in_sizes[4];         // 800000
    const int nb = (N + 255) >> 8;     // 196 coarse buckets

    // workspace layout
    char* wsb = (char*)d_ws;
    __half* Wh         = (__half*)wsb;           wsb += (size_t)N * NC * 2;
    float* s_src       = (float*)wsb;            wsb += (size_t)N * NH * 4;
    float* s_dst       = (float*)wsb;            wsb += (size_t)N * NH * 4;
    int* row_off       = (int*)wsb;              wsb += (size_t)(N + 1) * 4;
    int* bcnt          = (int*)wsb;              wsb += (size_t)256 * 4;
    unsigned* packed   = (unsigned*)wsb;         wsb += (size_t)nb * BCAP * 4;
    unsigned short* srcs = (unsigned short*)wsb; wsb += (size_t)E * 2;

    hipMemsetAsync(bcnt, 0, 256 * 4, stream);

    const int gemm_blocks = (N + GR - 1) / GR;          // 782
    const int scat_blocks = (E + EPB - 1) / EPB;        // 196
    gemm_s_scat_kernel<<<gemm_blocks + scat_blocks, 256, 0, stream>>>(
        h, W, a1, a2, src, dst, bcnt, packed, Wh, s_src, s_dst, N, E, gemm_blocks);

    bucketB_kernel<<<nb, 256, 0, stream>>>(packed, bcnt, row_off, srcs, N, E, nb);

    int g_blocks = (N + 3) / 4;
    gather_kernel<<<g_blocks, 256, 0, stream>>>(srcs, row_off, s_src, s_dst, Wh, out, N);
}

// Round 8
// 74.282 us; speedup vs baseline: 20.5413x; 1.1031x over previous
//
#include <hip/hip_runtime.h>
#include <hip/hip_bf16.h>
#include <hip/hip_fp16.h>

// GAT fused layer for MI355X — round 8: de-duplicated softmax in gather.
//   memset bcnt=0 (1 KB)
//   K1 gemm_s_scat : blocks [0,782): Wh(fp16) = h @ W' via mfma (+ s epilogue)
//                    blocks [782,978): coarse-bucket edge scatter (4096 edges each)
//   K2 bucketB     : per-bucket LDS counting sort (+ inline bcnt scan) -> srcs(u16) + row_off
//   K3 gather      : per dst-node wave; score phase computes p once per (edge,head)
//                    (8 edges x 8 heads = 64 lanes), PV phase broadcasts via shfl.

#define FIN 128
#define NH 8
#define NO 8
#define NC 64
#define GR 64     // gemm rows per block
#define EPB 4096  // edges per scatter block
#define BCAP 8192 // slots per coarse bucket (mean ~4082, sigma ~64)

typedef __attribute__((ext_vector_type(8))) short bf16x8;
typedef __attribute__((ext_vector_type(4))) float f32x4;

static __device__ __forceinline__ unsigned short f2bf(float f) {
    unsigned u = __float_as_uint(f);
    u += 0x7fff + ((u >> 16) & 1);
    return (unsigned short)(u >> 16);
}

__global__ __launch_bounds__(256) void gemm_s_scat_kernel(
    const float* __restrict__ h, const float* __restrict__ W,
    const float* __restrict__ a1, const float* __restrict__ a2,
    const int* __restrict__ src, const int* __restrict__ dst,
    int* __restrict__ bcnt, unsigned* __restrict__ packed,
    __half* __restrict__ Wh, float* __restrict__ s_src, float* __restrict__ s_dst,
    int N, int E, int gemm_blocks)
{
    __shared__ unsigned short hA[GR * FIN];   // 16 KB (scatter blocks alias counters here)
    __shared__ unsigned short wB[NC * FIN];   // 16 KB
    const int tid = threadIdx.x;

    if (blockIdx.x >= gemm_blocks) {
        // ---------------- scatter block: 4096 edges -> coarse buckets ----------------
        int* cnt_l  = (int*)hA;         // [256]
        int* base_l = cnt_l + 256;      // [256]
        const long e0 = (long)(blockIdx.x - gemm_blocks) * EPB;
        cnt_l[tid] = 0;
        __syncthreads();
        int br[16];        // (bucket<<16) | local rank
        unsigned pk[16];   // (dst&255)<<16 | src
#pragma unroll
        for (int j = 0; j < 16; ++j) {
            long e = e0 + j * 256 + tid;
            bool ok = (e < E);
            int d = ok ? dst[e] : 0;
            int s = ok ? src[e] : 0;
            int b = d >> 8;
            int r = ok ? atomicAdd(&cnt_l[b], 1) : 0;
            br[j] = ok ? ((b << 16) | r) : -1;
            pk[j] = ((unsigned)(d & 255) << 16) | (unsigned)s;   // src < 65536
        }
        __syncthreads();
        if (cnt_l[tid] > 0) base_l[tid] = atomicAdd(&bcnt[tid], cnt_l[tid]);
        __syncthreads();
#pragma unroll
        for (int j = 0; j < 16; ++j) {
            if (br[j] >= 0) {
                int b = br[j] >> 16, r = br[j] & 0xFFFF;
                packed[(long)b * BCAP + base_l[b] + r] = pk[j];
            }
        }
        return;
    }

    // ---------------- gemm block ----------------
    const int row0 = blockIdx.x * GR;
    {   // stage hA: row r=t>>2, k chunk (t&3)*32..+31, byte ^= (row&7)<<4
        int r = tid >> 2;
        int c0 = (tid & 3) * 32;
        int n = row0 + r;
        const float4* hp = (const float4*)(h + (long)n * FIN + c0);
        char* basep = (char*)hA + r * (FIN * 2);
        int sw = (r & 7) << 4;
#pragma unroll
        for (int j = 0; j < 8; ++j) {
            float4 v = (n < N) ? hp[j] : make_float4(0.f, 0.f, 0.f, 0.f);
            ushort4 b;
            b.x = f2bf(v.x); b.y = f2bf(v.y); b.z = f2bf(v.z); b.w = f2bf(v.w);
            int byte = (c0 + j * 4) * 2;
            *(ushort4*)(basep + (byte ^ sw)) = b;
        }
    }
    for (int i = tid; i < NH * FIN * NO; i += 256) {
        int hh = i >> 10, f = (i >> 3) & 127, o = i & 7;
        int c = hh * 8 + o;
        *(unsigned short*)((char*)wB + c * (FIN * 2) + ((f * 2) ^ ((c & 7) << 4))) = f2bf(W[i]);
    }
    __syncthreads();

    const int w    = tid >> 6;
    const int lane = tid & 63;
    const int l15  = lane & 15;
    const int lg   = lane >> 4;
    const int arow = w * 16 + l15;

    f32x4 acc[4] = {{0,0,0,0},{0,0,0,0},{0,0,0,0},{0,0,0,0}};
    const char* hbase = (const char*)hA + arow * (FIN * 2);
    const int hsw = (arow & 7) << 4;
#pragma unroll
    for (int kk = 0; kk < 4; ++kk) {
        int kb = kk * 64 + lg * 16;
        bf16x8 af = *(const bf16x8*)(hbase + (kb ^ hsw));
#pragma unroll
        for (int nt = 0; nt < 4; ++nt) {
            int c = nt * 16 + l15;
            bf16x8 bf = *(const bf16x8*)((const char*)wB + c * (FIN * 2) + (kb ^ ((c & 7) << 4)));
            acc[nt] = __builtin_amdgcn_mfma_f32_16x16x32_bf16(af, bf, acc[nt], 0, 0, 0);
        }
    }

    // epilogue: C/D layout col=lane&15, row=(lane>>4)*4+reg
#pragma unroll
    for (int nt = 0; nt < 4; ++nt) {
        int col = nt * 16 + l15;
        float a1c = a1[col];
        float a2c = a2[col];
#pragma unroll
        for (int r = 0; r < 4; ++r) {
            int n = row0 + w * 16 + lg * 4 + r;
            float v = acc[nt][r];
            bool ok = (n < N);
            if (ok) Wh[(long)n * NC + col] = __float2half_rn(v);
            float ps = v * a1c, pd = v * a2c;
            ps += __shfl_xor(ps, 1); pd += __shfl_xor(pd, 1);
            ps += __shfl_xor(ps, 2); pd += __shfl_xor(pd, 2);
            ps += __shfl_xor(ps, 4); pd += __shfl_xor(pd, 4);
            if (ok && (col & 7) == 0) {
                s_src[n * NH + (col >> 3)] = ps;
                s_dst[n * NH + (col >> 3)] = pd;
            }
        }
    }
}

// Per-bucket counting sort (+ inline exclusive scan of bcnt for the global base).
__global__ __launch_bounds__(256) void bucketB_kernel(
    const unsigned* __restrict__ packed, const int* __restrict__ bcnt,
    int* __restrict__ row_off, unsigned short* __restrict__ srcs,
    int N, int E, int nb)
{
    __shared__ int bins[256];
    __shared__ int scan_s[256];
    __shared__ int g0s;
    __shared__ unsigned short outb[BCAP];
    const int t = threadIdx.x;
    const int b = blockIdx.x;
    const int d0 = b << 8;
    const unsigned* pin = packed + (long)b * BCAP;

    // inline scan of bcnt -> this bucket's global base
    int v2 = (t < nb) ? bcnt[t] : 0;
    scan_s[t] = v2;
    __syncthreads();
    for (int off = 1; off < 256; off <<= 1) {
        int u = (t >= off) ? scan_s[t - off] : 0;
        __syncthreads();
        scan_s[t] += u;
        __syncthreads();
    }
    if (t == b) g0s = scan_s[t] - v2;   // exclusive prefix for bucket b
    bins[t] = 0;
    __syncthreads();
    const int g0 = g0s;
    const int cnt = bcnt[b];

    for (int i = t; i < cnt; i += 256)
        atomicAdd(&bins[pin[i] >> 16], 1);
    __syncthreads();
    int v = bins[t];
    scan_s[t] = v;
    __syncthreads();
    for (int off = 1; off < 256; off <<= 1) {
        int u = (t >= off) ? scan_s[t - off] : 0;
        __syncthreads();
        scan_s[t] += u;
        __syncthreads();
    }
    if (d0 + t < N) row_off[d0 + t] = g0 + scan_s[t] - v;   // exclusive
    if (b == nb - 1 && t == 0) row_off[N] = E;
    bins[t] = scan_s[t] - v;   // running cursor
    __syncthreads();
    for (int i = t; i < cnt; i += 256) {
        unsigned p = pin[i];
        int pos = atomicAdd(&bins[p >> 16], 1);
        outb[pos] = (unsigned short)(p & 0xFFFF);
    }
    __syncthreads();
    for (int i = t; i < cnt; i += 256)
        srcs[g0 + i] = outb[i];
}

// Per dst-node wave, two-phase:
//  score phase: lane = (edge-slot el=lane>>3, head hh=lane&7) computes p once per (edge,head)
//  PV phase:    per edge k: broadcast s_k, p_k(head) via shfl, coalesced 128B Wh row, 1 fma
__global__ __launch_bounds__(256) void gather_kernel(
    const unsigned short* __restrict__ srcs, const int* __restrict__ row_off,
    const float* __restrict__ s_src, const float* __restrict__ s_dst,
    const __half* __restrict__ Wh, float* __restrict__ out, int N)
{
    int wid = blockIdx.x * 4 + (threadIdx.x >> 6);   // one wave per dst node
    if (wid >= N) return;
    const int lane = threadIdx.x & 63;
    const int el = lane >> 3;   // edge slot within chunk
    const int hh = lane & 7;    // head (score phase)
    int beg = row_off[wid];
    int end = row_off[wid + 1];
    float sd = s_dst[wid * NH + hh];
    float acc = 0.f, den = 0.f;

    for (int i = beg; i < end; i += 8) {
        // ---- score phase: 8 edges x 8 heads ----
        int idx = i + el;
        bool val = (idx < end);
        int s = (int)srcs[val ? idx : beg];
        float ss = s_src[s * NH + hh];         // 32B-contiguous per 8-lane group
        float x = ss + sd;
        x = (x > 0.f) ? x : 0.2f * x;          // leaky_relu
        float p = __expf(x);                   // shift-invariant softmax, no max pass
        p = val ? p : 0.f;
        den += p;
        // ---- PV phase: one coalesced Wh row per edge ----
#pragma unroll
        for (int k = 0; k < 8; ++k) {
            int sk   = __shfl(s, k * 8);                   // edge k's src id
            float pk = __shfl(p, k * 8 + (lane >> 3));     // p(edge k, head of out-col)
            float wv = __half2float(Wh[((unsigned)sk << 6) | (unsigned)lane]);
            acc = fmaf(pk, wv, acc);
        }
    }
    // den currently per (el,hh); sum over edge-slot bits 3..5
    den += __shfl_xor(den, 8);
    den += __shfl_xor(den, 16);
    den += __shfl_xor(den, 32);
    float den_b = __shfl(den, lane >> 3);      // den for this out-col's head
    out[(unsigned)wid * NC + (unsigned)lane] = acc / fmaxf(den_b, 1e-16f);
}

extern "C" void kernel_launch(void* const* d_in, const int* in_sizes, int n_in,
                              void* d_out, int out_size, void* d_ws, size_t ws_size,
                              hipStream_t stream)
{
    const float* h  = (const float*)d_in[0];
    const float* W  = (const float*)d_in[1];
    const float* a1 = (const float*)d_in[2];
    const float* a2 = (const float*)d_in[3];
    const int*  src = (const int*)d_in[4];
    const int*  dst = (const int*)d_in[5];
    float* out = (float*)d_out;

    const int N = in_sizes[0] / FIN;   // 50000
    const int E = in_sizes[4];         // 800000
    const int nb = (N + 255) >> 8;     // 196 coarse buckets

    // workspace layout
    char* wsb = (char*)d_ws;
    __half* Wh         = (__half*)wsb;           wsb += (size_t)N * NC * 2;
    float* s_src       = (float*)wsb;            wsb += (size_t)N * NH * 4;
    float* s_dst       = (float*)wsb;            wsb += (size_t)N * NH * 4;
    int* row_off       = (int*)wsb;              wsb += (size_t)(N + 1) * 4;
    int* bcnt          = (int*)wsb;              wsb += (size_t)256 * 4;
    unsigned* packed   = (unsigned*)wsb;         wsb += (size_t)nb * BCAP * 4;
    unsigned short* srcs = (unsigned short*)wsb; wsb += (size_t)E * 2;

    hipMemsetAsync(bcnt, 0, 256 * 4, stream);

    const int gemm_blocks = (N + GR - 1) / GR;          // 782
    const int scat_blocks = (E + EPB - 1) / EPB;        // 196
    gemm_s_scat_kernel<<<gemm_blocks + scat_blocks, 256, 0, stream>>>(
        h, W, a1, a2, src, dst, bcnt, packed, Wh, s_src, s_dst, N, E, gemm_blocks);

    bucketB_kernel<<<nb, 256, 0, stream>>>(packed, bcnt, row_off, srcs, N, E, nb);

    int g_blocks = (N + 3) / 4;
    gather_kernel<<<g_blocks, 256, 0, stream>>>(srcs, row_off, s_src, s_dst, Wh, out, N);
}

// Round 9
// 72.852 us; speedup vs baseline: 20.9444x; 1.0196x over previous
//
#include <hip/hip_runtime.h>
#include <hip/hip_bf16.h>
#include <hip/hip_fp16.h>

// GAT fused layer for MI355X — round 9: epilogue-free GEMM (s-scores as B-columns).
//   K0 prep        : bcnt=0; W -> pre-swizzled bf16 wBg[64 cols]; U=[W@a1|W@a2] -> cols 64..79
//   K1 gemm_s_scat : blocks [0,782): [Wh | s_src | s_dst] = h @ [W' | U] via mfma (80 cols)
//                    blocks [782,978): coarse-bucket edge scatter (4096 edges each)
//   K2 bucketB     : per-bucket LDS counting sort (+ inline bcnt scan) -> srcs(u16) + row_off
//   K3 gather      : per dst-node wave; score phase 8 edges x 8 heads, PV phase via shfl

#define FIN 128
#define NH 8
#define NO 8
#define NC 64
#define NB_COLS 80   // 64 Wh cols + 16 score cols
#define GR 64        // gemm rows per block
#define EPB 4096     // edges per scatter block
#define BCAP 8192    // slots per coarse bucket (mean ~4082)

typedef __attribute__((ext_vector_type(8))) short bf16x8;
typedef __attribute__((ext_vector_type(4))) float f32x4;

static __device__ __forceinline__ unsigned short f2bf(float f) {
    unsigned u = __float_as_uint(f);
    u += 0x7fff + ((u >> 16) & 1);
    return (unsigned short)(u >> 16);
}

// One block. Zeros bcnt; converts W to swizzled bf16 [c][k] layout; computes U columns.
__global__ __launch_bounds__(256) void prep_kernel(
    const float* __restrict__ W, const float* __restrict__ a1, const float* __restrict__ a2,
    unsigned short* __restrict__ wBg, int* __restrict__ bcnt)
{
    const int t = threadIdx.x;
    bcnt[t] = 0;
    // W columns: c = h*8+o, element index k=f, swizzled: idx = f ^ ((c&7)<<3)
    for (int i = t; i < NH * FIN * NO; i += 256) {
        int hh = i >> 10, f = (i >> 3) & 127, o = i & 7;
        int c = hh * 8 + o;
        wBg[c * FIN + (f ^ ((c & 7) << 3))] = f2bf(W[i]);
    }
    // U columns: c = 64+j ; j<8 -> W[h]@a1[h] (h=j), j>=8 -> W[h]@a2[h] (h=j-8)
    for (int i = t; i < 16 * FIN; i += 256) {
        int j = i >> 7;
        int f = i & 127;
        int hh = j & 7;
        const float* av = (j < 8) ? (a1 + hh * NO) : (a2 + (hh)*NO);
        const float* wv = W + hh * (FIN * NO) + f * NO;
        float s = 0.f;
#pragma unroll
        for (int o = 0; o < 8; ++o) s += wv[o] * av[o];
        int c = 64 + j;
        wBg[c * FIN + (f ^ ((c & 7) << 3))] = f2bf(s);
    }
}

__global__ __launch_bounds__(256) void gemm_s_scat_kernel(
    const float* __restrict__ h, const unsigned short* __restrict__ wBg,
    const int* __restrict__ src, const int* __restrict__ dst,
    int* __restrict__ bcnt, unsigned* __restrict__ packed,
    __half* __restrict__ Wh, float* __restrict__ s_src, float* __restrict__ s_dst,
    int N, int E, int gemm_blocks)
{
    __shared__ alignas(16) unsigned short hA[GR * FIN];       // 16 KB (scatter aliases)
    __shared__ alignas(16) unsigned short wB[NB_COLS * FIN];  // 20 KB
    const int tid = threadIdx.x;

    if (blockIdx.x >= gemm_blocks) {
        // ---------------- scatter block: 4096 edges -> coarse buckets ----------------
        int* cnt_l  = (int*)hA;         // [256]
        int* base_l = cnt_l + 256;      // [256]
        const long e0 = (long)(blockIdx.x - gemm_blocks) * EPB;
        cnt_l[tid] = 0;
        __syncthreads();
        int br[16];        // (bucket<<16) | local rank
        unsigned pk[16];   // (dst&255)<<16 | src
#pragma unroll
        for (int j = 0; j < 16; ++j) {
            long e = e0 + j * 256 + tid;
            bool ok = (e < E);
            int d = ok ? dst[e] : 0;
            int s = ok ? src[e] : 0;
            int b = d >> 8;
            int r = ok ? atomicAdd(&cnt_l[b], 1) : 0;
            br[j] = ok ? ((b << 16) | r) : -1;
            pk[j] = ((unsigned)(d & 255) << 16) | (unsigned)s;   // src < 65536
        }
        __syncthreads();
        if (cnt_l[tid] > 0) base_l[tid] = atomicAdd(&bcnt[tid], cnt_l[tid]);
        __syncthreads();
#pragma unroll
        for (int j = 0; j < 16; ++j) {
            if (br[j] >= 0) {
                int b = br[j] >> 16, r = br[j] & 0xFFFF;
                packed[(long)b * BCAP + base_l[b] + r] = pk[j];
            }
        }
        return;
    }

    // ---------------- gemm block ----------------
    const int row0 = blockIdx.x * GR;
    {   // stage hA: row r=t>>2, k chunk (t&3)*32..+31, byte ^= (row&7)<<4
        int r = tid >> 2;
        int c0 = (tid & 3) * 32;
        int n = row0 + r;
        const float4* hp = (const float4*)(h + (long)n * FIN + c0);
        char* basep = (char*)hA + r * (FIN * 2);
        int sw = (r & 7) << 4;
#pragma unroll
        for (int j = 0; j < 8; ++j) {
            float4 v = (n < N) ? hp[j] : make_float4(0.f, 0.f, 0.f, 0.f);
            ushort4 b;
            b.x = f2bf(v.x); b.y = f2bf(v.y); b.z = f2bf(v.z); b.w = f2bf(v.w);
            int byte = (c0 + j * 4) * 2;
            *(ushort4*)(basep + (byte ^ sw)) = b;
        }
    }
    {   // stage wB: linear 16B copies of pre-swizzled wBg (20 KB)
        const uint4* s4 = (const uint4*)wBg;
        uint4* d4 = (uint4*)wB;
#pragma unroll
        for (int j = 0; j < 5; ++j)
            d4[j * 256 + tid] = s4[j * 256 + tid];
    }
    __syncthreads();

    const int w    = tid >> 6;
    const int lane = tid & 63;
    const int l15  = lane & 15;
    const int lg   = lane >> 4;
    const int arow = w * 16 + l15;

    f32x4 acc[5] = {{0,0,0,0},{0,0,0,0},{0,0,0,0},{0,0,0,0},{0,0,0,0}};
    const char* hbase = (const char*)hA + arow * (FIN * 2);
    const int hsw = (arow & 7) << 4;
#pragma unroll
    for (int kk = 0; kk < 4; ++kk) {
        int kb = kk * 64 + lg * 16;
        bf16x8 af = *(const bf16x8*)(hbase + (kb ^ hsw));
#pragma unroll
        for (int nt = 0; nt < 5; ++nt) {
            int c = nt * 16 + l15;
            bf16x8 bf = *(const bf16x8*)((const char*)wB + c * (FIN * 2) + (kb ^ ((c & 7) << 4)));
            acc[nt] = __builtin_amdgcn_mfma_f32_16x16x32_bf16(af, bf, acc[nt], 0, 0, 0);
        }
    }

    // epilogue (no cross-lane): C/D layout col=lane&15, row=(lane>>4)*4+reg
#pragma unroll
    for (int nt = 0; nt < 4; ++nt) {
        int col = nt * 16 + l15;
#pragma unroll
        for (int r = 0; r < 4; ++r) {
            int n = row0 + w * 16 + lg * 4 + r;
            if (n < N) Wh[(long)n * NC + col] = __float2half_rn(acc[nt][r]);
        }
    }
#pragma unroll
    for (int r = 0; r < 4; ++r) {
        int n = row0 + w * 16 + lg * 4 + r;
        if (n < N) {
            float v = acc[4][r];
            if (l15 < 8) s_src[n * NH + l15] = v;
            else         s_dst[n * NH + (l15 - 8)] = v;
        }
    }
}

// Per-bucket counting sort (+ inline exclusive scan of bcnt for the global base).
__global__ __launch_bounds__(256) void bucketB_kernel(
    const unsigned* __restrict__ packed, const int* __restrict__ bcnt,
    int* __restrict__ row_off, unsigned short* __restrict__ srcs,
    int N, int E, int nb)
{
    __shared__ int bins[256];
    __shared__ int scan_s[256];
    __shared__ int g0s;
    __shared__ unsigned short outb[BCAP];
    const int t = threadIdx.x;
    const int b = blockIdx.x;
    const int d0 = b << 8;
    const unsigned* pin = packed + (long)b * BCAP;

    // inline scan of bcnt -> this bucket's global base
    int v2 = (t < nb) ? bcnt[t] : 0;
    scan_s[t] = v2;
    __syncthreads();
    for (int off = 1; off < 256; off <<= 1) {
        int u = (t >= off) ? scan_s[t - off] : 0;
        __syncthreads();
        scan_s[t] += u;
        __syncthreads();
    }
    if (t == b) g0s = scan_s[t] - v2;   // exclusive prefix for bucket b
    bins[t] = 0;
    __syncthreads();
    const int g0 = g0s;
    const int cnt = bcnt[b];

    for (int i = t; i < cnt; i += 256)
        atomicAdd(&bins[pin[i] >> 16], 1);
    __syncthreads();
    int v = bins[t];
    scan_s[t] = v;
    __syncthreads();
    for (int off = 1; off < 256; off <<= 1) {
        int u = (t >= off) ? scan_s[t - off] : 0;
        __syncthreads();
        scan_s[t] += u;
        __syncthreads();
    }
    if (d0 + t < N) row_off[d0 + t] = g0 + scan_s[t] - v;   // exclusive
    if (b == nb - 1 && t == 0) row_off[N] = E;
    bins[t] = scan_s[t] - v;   // running cursor
    __syncthreads();
    for (int i = t; i < cnt; i += 256) {
        unsigned p = pin[i];
        int pos = atomicAdd(&bins[p >> 16], 1);
        outb[pos] = (unsigned short)(p & 0xFFFF);
    }
    __syncthreads();
    for (int i = t; i < cnt; i += 256)
        srcs[g0 + i] = outb[i];
}

// Per dst-node wave, two-phase:
//  score phase: lane = (edge-slot el=lane>>3, head hh=lane&7) computes p once per (edge,head)
//  PV phase:    per edge k: broadcast s_k, p_k(head) via shfl, coalesced 128B Wh row, 1 fma
__global__ __launch_bounds__(256) void gather_kernel(
    const unsigned short* __restrict__ srcs, const int* __restrict__ row_off,
    const float* __restrict__ s_src, const float* __restrict__ s_dst,
    const __half* __restrict__ Wh, float* __restrict__ out, int N)
{
    int wid = blockIdx.x * 4 + (threadIdx.x >> 6);   // one wave per dst node
    if (wid >= N) return;
    const int lane = threadIdx.x & 63;
    const int el = lane >> 3;   // edge slot within chunk
    const int hh = lane & 7;    // head (score phase)
    int beg = row_off[wid];
    int end = row_off[wid + 1];
    float sd = s_dst[wid * NH + hh];
    float acc = 0.f, den = 0.f;

    for (int i = beg; i < end; i += 8) {
        // ---- score phase: 8 edges x 8 heads ----
        int idx = i + el;
        bool val = (idx < end);
        int s = (int)srcs[val ? idx : beg];
        float ss = s_src[s * NH + hh];
        float x = ss + sd;
        x = (x > 0.f) ? x : 0.2f * x;          // leaky_relu
        float p = __expf(x);                   // shift-invariant softmax, no max pass
        p = val ? p : 0.f;
        den += p;
        // ---- PV phase: one coalesced Wh row per edge ----
#pragma unroll
        for (int k = 0; k < 8; ++k) {
            int sk   = __shfl(s, k * 8);                   // edge k's src id
            float pk = __shfl(p, k * 8 + (lane >> 3));     // p(edge k, head of out-col)
            float wv = __half2float(Wh[((unsigned)sk << 6) | (unsigned)lane]);
            acc = fmaf(pk, wv, acc);
        }
    }
    // den currently per (el,hh); sum over edge-slot bits 3..5
    den += __shfl_xor(den, 8);
    den += __shfl_xor(den, 16);
    den += __shfl_xor(den, 32);
    float den_b = __shfl(den, lane >> 3);      // den for this out-col's head
    out[(unsigned)wid * NC + (unsigned)lane] = acc / fmaxf(den_b, 1e-16f);
}

extern "C" void kernel_launch(void* const* d_in, const int* in_sizes, int n_in,
                              void* d_out, int out_size, void* d_ws, size_t ws_size,
                              hipStream_t stream)
{
    const float* h  = (const float*)d_in[0];
    const float* W  = (const float*)d_in[1];
    const float* a1 = (const float*)d_in[2];
    const float* a2 = (const float*)d_in[3];
    const int*  src = (const int*)d_in[4];
    const int*  dst = (const int*)d_in[5];
    float* out = (float*)d_out;

    const int N = in_sizes[0] / FIN;   // 50000
    const int E = in_sizes[4];         // 800000
    const int nb = (N + 255) >> 8;     // 196 coarse buckets

    // workspace layout
    char* wsb = (char*)d_ws;
    __half* Wh         = (__half*)wsb;           wsb += (size_t)N * NC * 2;
    float* s_src       = (float*)wsb;            wsb += (size_t)N * NH * 4;
    float* s_dst       = (float*)wsb;            wsb += (size_t)N * NH * 4;
    int* row_off       = (int*)wsb;              wsb += (size_t)(N + 1) * 4;
    int* bcnt          = (int*)wsb;              wsb += (size_t)256 * 4;
    unsigned short* wBg = (unsigned short*)wsb;  wsb += (size_t)NB_COLS * FIN * 2;
    unsigned* packed   = (unsigned*)wsb;         wsb += (size_t)nb * BCAP * 4;
    unsigned short* srcs = (unsigned short*)wsb; wsb += (size_t)E * 2;

    prep_kernel<<<1, 256, 0, stream>>>(W, a1, a2, wBg, bcnt);

    const int gemm_blocks = (N + GR - 1) / GR;          // 782
    const int scat_blocks = (E + EPB - 1) / EPB;        // 196
    gemm_s_scat_kernel<<<gemm_blocks + scat_blocks, 256, 0, stream>>>(
        h, wBg, src, dst, bcnt, packed, Wh, s_src, s_dst, N, E, gemm_blocks);

    bucketB_kernel<<<nb, 256, 0, stream>>>(packed, bcnt, row_off, srcs, N, E, nb);

    int g_blocks = (N + 3) / 4;
    gather_kernel<<<g_blocks, 256, 0, stream>>>(srcs, row_off, s_src, s_dst, Wh, out, N);
}

// Round 10
// 70.712 us; speedup vs baseline: 21.5783x; 1.0303x over previous
//
#include <hip/hip_runtime.h>
#include <hip/hip_bf16.h>
#include <hip/hip_fp16.h>

// GAT fused layer for MI355X — round 10: A-staging-free MFMA GEMM (direct global A-frags).
//   K0 prep        : bcnt=0; W -> pre-swizzled bf16 wBg[64 cols]; U=[W@a1|W@a2] -> cols 64..79
//   K1 gemm_s_scat : blocks [0,782): [Wh | s] = h @ [W' | U]; A-frags loaded straight from
//                    global (32B/lane, 16x128B segments per wave/kk), B from 20KB LDS.
//                    blocks [782,978): coarse-bucket edge scatter (4096 edges each)
//   K2 bucketB     : per-bucket LDS counting sort (+ inline bcnt scan) -> srcs(u16) + row_off
//   K3 gather      : per dst-node wave; score phase 8 edges x 8 heads, PV phase via shfl

#define FIN 128
#define NH 8
#define NO 8
#define NC 64
#define NB_COLS 80   // 64 Wh cols + 16 score cols
#define GR 64        // gemm rows per block
#define EPB 4096     // edges per scatter block
#define BCAP 8192    // slots per coarse bucket (mean ~4082)

typedef __attribute__((ext_vector_type(8))) short bf16x8;
typedef __attribute__((ext_vector_type(4))) float f32x4;

static __device__ __forceinline__ unsigned short f2bf(float f) {
    unsigned u = __float_as_uint(f);
    u += 0x7fff + ((u >> 16) & 1);
    return (unsigned short)(u >> 16);
}

// One block. Zeros bcnt; converts W to swizzled bf16 [c][k] layout; computes U columns.
__global__ __launch_bounds__(256) void prep_kernel(
    const float* __restrict__ W, const float* __restrict__ a1, const float* __restrict__ a2,
    unsigned short* __restrict__ wBg, int* __restrict__ bcnt)
{
    const int t = threadIdx.x;
    bcnt[t] = 0;
    // W columns: c = h*8+o, element index k=f, swizzled: idx = f ^ ((c&7)<<3)
    for (int i = t; i < NH * FIN * NO; i += 256) {
        int hh = i >> 10, f = (i >> 3) & 127, o = i & 7;
        int c = hh * 8 + o;
        wBg[c * FIN + (f ^ ((c & 7) << 3))] = f2bf(W[i]);
    }
    // U columns: c = 64+j ; j<8 -> W[h]@a1[h] (h=j), j>=8 -> W[h]@a2[h] (h=j-8)
    for (int i = t; i < 16 * FIN; i += 256) {
        int j = i >> 7;
        int f = i & 127;
        int hh = j & 7;
        const float* av = (j < 8) ? (a1 + hh * NO) : (a2 + hh * NO);
        const float* wv = W + hh * (FIN * NO) + f * NO;
        float s = 0.f;
#pragma unroll
        for (int o = 0; o < 8; ++o) s += wv[o] * av[o];
        int c = 64 + j;
        wBg[c * FIN + (f ^ ((c & 7) << 3))] = f2bf(s);
    }
}

__global__ __launch_bounds__(256) void gemm_s_scat_kernel(
    const float* __restrict__ h, const unsigned short* __restrict__ wBg,
    const int* __restrict__ src, const int* __restrict__ dst,
    int* __restrict__ bcnt, unsigned* __restrict__ packed,
    __half* __restrict__ Wh, float* __restrict__ s_src, float* __restrict__ s_dst,
    int N, int E, int gemm_blocks)
{
    __shared__ alignas(16) unsigned short wB[NB_COLS * FIN];  // 20 KB
    __shared__ int cnt_l[256];    // scatter blocks only
    __shared__ int base_l[256];
    const int tid = threadIdx.x;

    if (blockIdx.x >= gemm_blocks) {
        // ---------------- scatter block: 4096 edges -> coarse buckets ----------------
        const long e0 = (long)(blockIdx.x - gemm_blocks) * EPB;
        cnt_l[tid] = 0;
        __syncthreads();
        int br[16];        // (bucket<<16) | local rank
        unsigned pk[16];   // (dst&255)<<16 | src
#pragma unroll
        for (int j = 0; j < 16; ++j) {
            long e = e0 + j * 256 + tid;
            bool ok = (e < E);
            int d = ok ? dst[e] : 0;
            int s = ok ? src[e] : 0;
            int b = d >> 8;
            int r = ok ? atomicAdd(&cnt_l[b], 1) : 0;
            br[j] = ok ? ((b << 16) | r) : -1;
            pk[j] = ((unsigned)(d & 255) << 16) | (unsigned)s;   // src < 65536
        }
        __syncthreads();
        if (cnt_l[tid] > 0) base_l[tid] = atomicAdd(&bcnt[tid], cnt_l[tid]);
        __syncthreads();
#pragma unroll
        for (int j = 0; j < 16; ++j) {
            if (br[j] >= 0) {
                int b = br[j] >> 16, r = br[j] & 0xFFFF;
                packed[(long)b * BCAP + base_l[b] + r] = pk[j];
            }
        }
        return;
    }

    // ---------------- gemm block ----------------
    const int w    = tid >> 6;
    const int lane = tid & 63;
    const int l15  = lane & 15;
    const int lg   = lane >> 4;

    // A-fragments straight from global: lane reads 8x16B (4 kk x 32B contiguous).
    const int row  = blockIdx.x * GR + w * 16 + l15;
    const int rowc = (row < N) ? row : (N - 1);        // clamp (masked at store)
    const float* hrow = h + (long)rowc * FIN + lg * 8;
    float4 va[8];
#pragma unroll
    for (int kk = 0; kk < 4; ++kk) {
        va[2 * kk]     = *(const float4*)(hrow + kk * 32);
        va[2 * kk + 1] = *(const float4*)(hrow + kk * 32 + 4);
    }

    {   // stage wB: linear 16B copies of pre-swizzled wBg (20 KB, L2-resident)
        const uint4* s4 = (const uint4*)wBg;
        uint4* d4 = (uint4*)wB;
#pragma unroll
        for (int j = 0; j < 5; ++j)
            d4[j * 256 + tid] = s4[j * 256 + tid];
    }
    __syncthreads();

    // convert to bf16 fragments in registers
    bf16x8 af[4];
#pragma unroll
    for (int kk = 0; kk < 4; ++kk) {
        bf16x8 r;
        r[0] = (short)f2bf(va[2 * kk].x);     r[1] = (short)f2bf(va[2 * kk].y);
        r[2] = (short)f2bf(va[2 * kk].z);     r[3] = (short)f2bf(va[2 * kk].w);
        r[4] = (short)f2bf(va[2 * kk + 1].x); r[5] = (short)f2bf(va[2 * kk + 1].y);
        r[6] = (short)f2bf(va[2 * kk + 1].z); r[7] = (short)f2bf(va[2 * kk + 1].w);
        af[kk] = r;
    }

    f32x4 acc[5] = {{0,0,0,0},{0,0,0,0},{0,0,0,0},{0,0,0,0},{0,0,0,0}};
#pragma unroll
    for (int kk = 0; kk < 4; ++kk) {
        int kb = kk * 64 + lg * 16;
#pragma unroll
        for (int nt = 0; nt < 5; ++nt) {
            int c = nt * 16 + l15;
            bf16x8 bf = *(const bf16x8*)((const char*)wB + c * (FIN * 2) + (kb ^ ((c & 7) << 4)));
            acc[nt] = __builtin_amdgcn_mfma_f32_16x16x32_bf16(af[kk], bf, acc[nt], 0, 0, 0);
        }
    }

    // epilogue (no cross-lane): C/D layout col=lane&15, row=(lane>>4)*4+reg
    const int row0 = blockIdx.x * GR;
#pragma unroll
    for (int nt = 0; nt < 4; ++nt) {
        int col = nt * 16 + l15;
#pragma unroll
        for (int r = 0; r < 4; ++r) {
            int n = row0 + w * 16 + lg * 4 + r;
            if (n < N) Wh[(long)n * NC + col] = __float2half_rn(acc[nt][r]);
        }
    }
#pragma unroll
    for (int r = 0; r < 4; ++r) {
        int n = row0 + w * 16 + lg * 4 + r;
        if (n < N) {
            float v = acc[4][r];
            if (l15 < 8) s_src[n * NH + l15] = v;
            else         s_dst[n * NH + (l15 - 8)] = v;
        }
    }
}

// Per-bucket counting sort (+ inline exclusive scan of bcnt for the global base).
__global__ __launch_bounds__(256) void bucketB_kernel(
    const unsigned* __restrict__ packed, const int* __restrict__ bcnt,
    int* __restrict__ row_off, unsigned short* __restrict__ srcs,
    int N, int E, int nb)
{
    __shared__ int bins[256];
    __shared__ int scan_s[256];
    __shared__ int g0s;
    __shared__ unsigned short outb[BCAP];
    const int t = threadIdx.x;
    const int b = blockIdx.x;
    const int d0 = b << 8;
    const unsigned* pin = packed + (long)b * BCAP;

    // inline scan of bcnt -> this bucket's global base
    int v2 = (t < nb) ? bcnt[t] : 0;
    scan_s[t] = v2;
    __syncthreads();
    for (int off = 1; off < 256; off <<= 1) {
        int u = (t >= off) ? scan_s[t - off] : 0;
        __syncthreads();
        scan_s[t] += u;
        __syncthreads();
    }
    if (t == b) g0s = scan_s[t] - v2;   // exclusive prefix for bucket b
    bins[t] = 0;
    __syncthreads();
    const int g0 = g0s;
    const int cnt = bcnt[b];

    for (int i = t; i < cnt; i += 256)
        atomicAdd(&bins[pin[i] >> 16], 1);
    __syncthreads();
    int v = bins[t];
    scan_s[t] = v;
    __syncthreads();
    for (int off = 1; off < 256; off <<= 1) {
        int u = (t >= off) ? scan_s[t - off] : 0;
        __syncthreads();
        scan_s[t] += u;
        __syncthreads();
    }
    if (d0 + t < N) row_off[d0 + t] = g0 + scan_s[t] - v;   // exclusive
    if (b == nb - 1 && t == 0) row_off[N] = E;
    bins[t] = scan_s[t] - v;   // running cursor
    __syncthreads();
    for (int i = t; i < cnt; i += 256) {
        unsigned p = pin[i];
        int pos = atomicAdd(&bins[p >> 16], 1);
        outb[pos] = (unsigned short)(p & 0xFFFF);
    }
    __syncthreads();
    for (int i = t; i < cnt; i += 256)
        srcs[g0 + i] = outb[i];
}

// Per dst-node wave, two-phase:
//  score phase: lane = (edge-slot el=lane>>3, head hh=lane&7) computes p once per (edge,head)
//  PV phase:    per edge k: broadcast s_k, p_k(head) via shfl, coalesced 128B Wh row, 1 fma
__global__ __launch_bounds__(256) void gather_kernel(
    const unsigned short* __restrict__ srcs, const int* __restrict__ row_off,
    const float* __restrict__ s_src, const float* __restrict__ s_dst,
    const __half* __restrict__ Wh, float* __restrict__ out, int N)
{
    int wid = blockIdx.x * 4 + (threadIdx.x >> 6);   // one wave per dst node
    if (wid >= N) return;
    const int lane = threadIdx.x & 63;
    const int el = lane >> 3;   // edge slot within chunk
    const int hh = lane & 7;    // head (score phase)
    int beg = row_off[wid];
    int end = row_off[wid + 1];
    float sd = s_dst[wid * NH + hh];
    float acc = 0.f, den = 0.f;

    for (int i = beg; i < end; i += 8) {
        // ---- score phase: 8 edges x 8 heads ----
        int idx = i + el;
        bool val = (idx < end);
        int s = (int)srcs[val ? idx : beg];
        float ss = s_src[s * NH + hh];
        float x = ss + sd;
        x = (x > 0.f) ? x : 0.2f * x;          // leaky_relu
        float p = __expf(x);                   // shift-invariant softmax, no max pass
        p = val ? p : 0.f;
        den += p;
        // ---- PV phase: one coalesced Wh row per edge ----
#pragma unroll
        for (int k = 0; k < 8; ++k) {
            int sk   = __shfl(s, k * 8);                   // edge k's src id
            float pk = __shfl(p, k * 8 + (lane >> 3));     // p(edge k, head of out-col)
            float wv = __half2float(Wh[((unsigned)sk << 6) | (unsigned)lane]);
            acc = fmaf(pk, wv, acc);
        }
    }
    // den currently per (el,hh); sum over edge-slot bits 3..5
    den += __shfl_xor(den, 8);
    den += __shfl_xor(den, 16);
    den += __shfl_xor(den, 32);
    float den_b = __shfl(den, lane >> 3);      // den for this out-col's head
    out[(unsigned)wid * NC + (unsigned)lane] = acc / fmaxf(den_b, 1e-16f);
}

extern "C" void kernel_launch(void* const* d_in, const int* in_sizes, int n_in,
                              void* d_out, int out_size, void* d_ws, size_t ws_size,
                              hipStream_t stream)
{
    const float* h  = (const float*)d_in[0];
    const float* W  = (const float*)d_in[1];
    const float* a1 = (const float*)d_in[2];
    const float* a2 = (const float*)d_in[3];
    const int*  src = (const int*)d_in[4];
    const int*  dst = (const int*)d_in[5];
    float* out = (float*)d_out;

    const int N = in_sizes[0] / FIN;   // 50000
    const int E = in_sizes[4];         // 800000
    const int nb = (N + 255) >> 8;     // 196 coarse buckets

    // workspace layout
    char* wsb = (char*)d_ws;
    __half* Wh         = (__half*)wsb;           wsb += (size_t)N * NC * 2;
    float* s_src       = (float*)wsb;            wsb += (size_t)N * NH * 4;
    float* s_dst       = (float*)wsb;            wsb += (size_t)N * NH * 4;
    int* row_off       = (int*)wsb;              wsb += (size_t)(N + 1) * 4;
    int* bcnt          = (int*)wsb;              wsb += (size_t)256 * 4;
    unsigned short* wBg = (unsigned short*)wsb;  wsb += (size_t)NB_COLS * FIN * 2;
    unsigned* packed   = (unsigned*)wsb;         wsb += (size_t)nb * BCAP * 4;
    unsigned short* srcs = (unsigned short*)wsb; wsb += (size_t)E * 2;

    prep_kernel<<<1, 256, 0, stream>>>(W, a1, a2, wBg, bcnt);

    const int gemm_blocks = (N + GR - 1) / GR;          // 782
    const int scat_blocks = (E + EPB - 1) / EPB;        // 196
    gemm_s_scat_kernel<<<gemm_blocks + scat_blocks, 256, 0, stream>>>(
        h, wBg, src, dst, bcnt, packed, Wh, s_src, s_dst, N, E, gemm_blocks);

    bucketB_kernel<<<nb, 256, 0, stream>>>(packed, bcnt, row_off, srcs, N, E, nb);

    int g_blocks = (N + 3) / 4;
    gather_kernel<<<g_blocks, 256, 0, stream>>>(srcs, row_off, s_src, s_dst, Wh, out, N);
}